// Round 1
// baseline (1103.399 us; speedup 1.0000x reference)
//
#include <hip/hip_runtime.h>
#include <hip/hip_bf16.h>

namespace {

constexpr int DIM_   = 512;
constexpr int KALL   = 11;
constexpr int DOM    = 10;
constexpr int NPROBE = 128;
constexpr int NGAL   = 64;
constexpr int NSETS  = 192;
constexpr int LPR    = 256;
constexpr int LGA    = 512;
constexpr int NCOL   = 192;   // batched-GEMM N (one column per set)

// Output layout (flat, reference return order)
constexpr size_t O_OUT1 = 0;                               // [128,4,512]
constexpr size_t O_OUT2 = (size_t)NPROBE * 4 * DIM_;       // 262144, [11,10]
constexpr size_t O_OUT3 = O_OUT2 + KALL * DOM;             // 262254, [64,4,512]
constexpr size_t O_OUT4 = O_OUT3 + (size_t)NGAL * 4 * DIM_;// 393326, [11,10]

// Workspace layout (float indices; flag int lives at byte 0)
constexpr size_t OFF_TPP  = 64;                       // 110 f (normalized proxy transforms, probe)
constexpr size_t OFF_TPG  = 192;                      // 110 f
constexpr size_t OFF_S0   = 320;                      // 192*4 f (bias·ctx offsets)
constexpr size_t OFF_IDX  = 1152;                     // 192*4 int
constexpr size_t OFF_MEAN = 2048;                     // [512][192] f (transposed)
constexpr size_t OFF_VAR  = OFF_MEAN + (size_t)DIM_ * NCOL;
constexpr size_t OFF_H1   = OFF_VAR + (size_t)DIM_ * NCOL;          // [11][1024][192]
constexpr size_t OFF_H2   = OFF_H1 + (size_t)KALL * 1024 * NCOL;    // [11][1024][192]
constexpr size_t OFF_CTX  = OFF_H2 + (size_t)KALL * 1024 * NCOL;    // [11][512][192]
constexpr size_t OFF_CFIN = OFF_CTX + (size_t)KALL * 512 * NCOL;    // [192][4][512]
constexpr size_t WS_FLOATS = OFF_CFIN + (size_t)NSETS * 4 * DIM_;
constexpr size_t WS_BYTES  = WS_FLOATS * 4;

__device__ __forceinline__ float cvt(float x) { return x; }
__device__ __forceinline__ float cvt(__hip_bfloat16 x) { return __bfloat162float(x); }
__device__ __forceinline__ void stor(float* p, float v) { *p = v; }
__device__ __forceinline__ void stor(__hip_bfloat16* p, float v) { *p = __float2bfloat16(v); }

template <typename T> struct IsBf16 { static constexpr int v = (sizeof(T) == 2) ? 1 : 0; };

// ---------------- dtype detector ----------------
// probe_W is the 512x512 identity. fp32: word0 = 0x3F800000 (1.0f).
// bf16 packed: word0 = (bf16)0.0 <<16 | (bf16)1.0 = 0x00003F80.
__global__ void detect_kernel(const unsigned int* probeW_bits, int* flag) {
    if (threadIdx.x == 0) *flag = (probeW_bits[0] == 0x3F800000u) ? 0 : 1;
}

// ---------------- proxies: out2/out4 + normalized tp ----------------
template <typename T>
__global__ void proxies_kernel(const int* flag, const T* pp, const T* pg,
                               const T* tW, const T* tb, float* wsf, T* dout) {
    if (*flag != IsBf16<T>::v) return;
    __shared__ float raw[2 * KALL * DOM];
    int t = threadIdx.x;
    if (t < 2 * KALL * DOM) {
        int fam = t / (KALL * DOM);
        int rem = t % (KALL * DOM);
        int i = rem / DOM, r = rem % DOM;
        const T* src = fam ? pg : pp;
        float acc = cvt(tb[r]);
        for (int d = 0; d < DIM_; ++d) acc += cvt(src[i * DIM_ + d]) * cvt(tW[r * DIM_ + d]);
        raw[t] = acc;
        size_t base = fam ? O_OUT4 : O_OUT2;
        stor(dout + base + i * DOM + r, acc);
    }
    __syncthreads();
    if (t < 2 * KALL) {
        int fam = t / KALL, i = t % KALL;
        const float* rw = raw + fam * KALL * DOM + i * DOM;
        float n = 0.f;
        for (int r = 0; r < DOM; ++r) n += rw[r] * rw[r];
        float inv = 1.0f / fmaxf(sqrtf(n), 1e-12f);
        float* dst = (fam ? wsf + OFF_TPG : wsf + OFF_TPP) + i * DOM;
        for (int r = 0; r < DOM; ++r) dst[r] = rw[r] * inv;
    }
}

// ---------------- per-set stats: gsim -> top4, mean/var (transposed) ----------------
template <typename T>
__global__ void stats_kernel(const int* flag, const T* probes, const T* gallery,
                             const int* plen, const int* glen, const T* tW,
                             const float* tp_p, const float* tp_g,
                             float* meanT, float* varT, int* idx4) {
    if (*flag != IsBf16<T>::v) return;
    int set = blockIdx.x;
    bool probe = set < NPROBE;
    int L = probe ? LPR : LGA;
    const T* feat = probe ? probes + (size_t)set * L * DIM_
                          : gallery + (size_t)(set - NPROBE) * L * DIM_;
    int len = probe ? plen[set] : glen[set - NPROBE];
    int len_eff = min(max(len, 1), L);
    float lp = (float)max(len, 1);

    __shared__ float tpl[KALL * DOM];
    __shared__ float ssum[DIM_];
    __shared__ float ssq[DIM_];
    __shared__ float gsim[KALL];

    int tid = threadIdx.x;
    const float* tp = probe ? tp_p : tp_g;
    if (tid < KALL * DOM) tpl[tid] = tp[tid];
    for (int i = tid; i < DIM_; i += 256) { ssum[i] = 0.f; ssq[i] = 0.f; }
    if (tid < KALL) gsim[tid] = 0.f;
    __syncthreads();

    int wave = tid >> 6, lane = tid & 63;
    // preload transform rows into registers: lane owns dims d = lane + 64*j
    float wreg[DOM][8];
#pragma unroll
    for (int r = 0; r < DOM; ++r)
#pragma unroll
        for (int j = 0; j < 8; ++j) wreg[r][j] = cvt(tW[r * DIM_ + lane + 64 * j]);

    float asum[8] = {0, 0, 0, 0, 0, 0, 0, 0};
    float asq[8] = {0, 0, 0, 0, 0, 0, 0, 0};
    float gacc = 0.f;

    for (int l = wave; l < len_eff; l += 4) {
        const T* row = feat + (size_t)l * DIM_;
        float f[8];
#pragma unroll
        for (int j = 0; j < 8; ++j) f[j] = cvt(row[lane + 64 * j]);
        float t[DOM];
#pragma unroll
        for (int r = 0; r < DOM; ++r) {
            float s = 0.f;
#pragma unroll
            for (int j = 0; j < 8; ++j) s += f[j] * wreg[r][j];
            t[r] = s;
        }
#pragma unroll
        for (int j = 0; j < 8; ++j) { asum[j] += f[j]; asq[j] += f[j] * f[j]; }
#pragma unroll
        for (int off = 32; off >= 1; off >>= 1) {
#pragma unroll
            for (int r = 0; r < DOM; ++r) t[r] += __shfl_xor(t[r], off, 64);
        }
        float nn = 0.f;
#pragma unroll
        for (int r = 0; r < DOM; ++r) nn += t[r] * t[r];
        float inv = 1.0f / fmaxf(sqrtf(nn), 1e-12f);
        if (lane < KALL) {
            float s = 0.f;
#pragma unroll
            for (int r = 0; r < DOM; ++r) s += t[r] * tpl[lane * DOM + r];
            gacc += s * inv;
        }
    }
    if (lane < KALL) atomicAdd(&gsim[lane], gacc);
#pragma unroll
    for (int j = 0; j < 8; ++j) {
        atomicAdd(&ssum[lane + 64 * j], asum[j]);
        atomicAdd(&ssq[lane + 64 * j], asq[j]);
    }
    __syncthreads();

    for (int d = tid; d < DIM_; d += 256) {
        float m = ssum[d] / lp;
        float v = ssq[d] / lp - m * m;
        meanT[(size_t)d * NCOL + set] = m;
        varT[(size_t)d * NCOL + set] = v;
    }
    if (tid == 0) {
        float g[KALL];
        for (int i = 0; i < KALL; ++i) g[i] = gsim[i];
        for (int kk = 0; kk < 4; ++kk) {
            int bi = 0;
            float bv = g[0];
            for (int i = 1; i < KALL; ++i)
                if (g[i] > bv) { bv = g[i]; bi = i; }   // strict > : lowest index wins ties
            idx4[set * 4 + kk] = bi;
            g[bi] = -3e38f;
        }
    }
}

// ---------------- batched expert MLP layer (all 11 experts x 192 sets) ----------------
// Y[e][m][s] = leaky( sum_k W[e][m][k] * X[e][k][s] + b[e][m] ), leaky slope 0.01
// Layer 1's X is virtual: [mean_s | var_s | proxies_fam(e)]
template <typename T, int LAYER1>
__global__ void mlp_kernel(const int* flag, const T* W, const T* bias,
                           const float* Xin, const float* meanT, const float* varT,
                           const T* pp, const T* pg, float* Y, int M, int K) {
    if (*flag != IsBf16<T>::v) return;
    __shared__ float Wt[16][68];  // [k][m] transposed tile
    __shared__ float Xt[16][68];  // [k][s]
    int tid = threadIdx.x;
    int tx = tid & 15, ty = tid >> 4;
    int e = blockIdx.z, m0 = blockIdx.y * 64, s0 = blockIdx.x * 64;
    float acc[4][4] = {};
    int wrow = tid >> 2, wcol = (tid & 3) * 4;
    int xrow = tid >> 4, xcol = (tid & 15) * 4;
    const size_t Wbase = ((size_t)e * M + m0 + wrow) * K + wcol;

    for (int k0 = 0; k0 < K; k0 += 16) {
        __syncthreads();
        const T* wp = W + Wbase + k0;
#pragma unroll
        for (int j = 0; j < 4; ++j) Wt[wcol + j][wrow] = cvt(wp[j]);
        int kk = k0 + xrow;
#pragma unroll
        for (int j = 0; j < 4; ++j) {
            int s = s0 + xcol + j;
            float x;
            if (LAYER1) {
                if (kk < DIM_)          x = meanT[(size_t)kk * NCOL + s];
                else if (kk < 2 * DIM_) x = varT[(size_t)(kk - DIM_) * NCOL + s];
                else x = cvt((s < NPROBE ? pp : pg)[e * DIM_ + kk - 2 * DIM_]);
            } else {
                x = Xin[((size_t)e * K + kk) * NCOL + s];
            }
            Xt[xrow][xcol + j] = x;
        }
        __syncthreads();
#pragma unroll
        for (int kq = 0; kq < 16; ++kq) {
            float a[4], b[4];
#pragma unroll
            for (int i = 0; i < 4; ++i) a[i] = Wt[kq][ty * 4 + i];
#pragma unroll
            for (int j = 0; j < 4; ++j) b[j] = Xt[kq][tx * 4 + j];
#pragma unroll
            for (int i = 0; i < 4; ++i)
#pragma unroll
                for (int j = 0; j < 4; ++j) acc[i][j] += a[i] * b[j];
        }
    }
#pragma unroll
    for (int i = 0; i < 4; ++i) {
        int m = m0 + ty * 4 + i;
        float bv = cvt(bias[(size_t)e * M + m]);
#pragma unroll
        for (int j = 0; j < 4; ++j) {
            float v = acc[i][j] + bv;
            v = v > 0.f ? v : 0.01f * v;
            Y[((size_t)e * M + m) * NCOL + s0 + tx * 4 + j] = v;
        }
    }
}

// ---------------- gather selected ctx; fold probe_W/probe_b into ctx ----------------
// scores = (feat @ Wp.T + pb) @ ctx.T  ==  feat @ (ctx @ Wp).T + (pb . ctx)
template <typename T>
__global__ void ctx_kernel(const int* flag, const float* CTX, const int* idx4,
                           const T* pW, const T* pb, float* cfin, float* s0v) {
    if (*flag != IsBf16<T>::v) return;
    int set = blockIdx.x, tid = threadIdx.x;
    bool probe = set < NPROBE;
    __shared__ float c4[4 * DIM_];
    __shared__ int eid[4];
    __shared__ float red[256];
    if (tid < 4) eid[tid] = idx4[set * 4 + tid];
    __syncthreads();
    for (int p = tid; p < 4 * DIM_; p += 256) {
        int k = p >> 9, d = p & 511;
        c4[p] = CTX[((size_t)eid[k] * DIM_ + d) * NCOL + set];
    }
    __syncthreads();
    if (probe) {
        float a0[4] = {0, 0, 0, 0}, a1[4] = {0, 0, 0, 0};
        for (int j = 0; j < DIM_; ++j) {
            float w0 = cvt(pW[(size_t)j * DIM_ + tid]);
            float w1 = cvt(pW[(size_t)j * DIM_ + tid + 256]);
#pragma unroll
            for (int k = 0; k < 4; ++k) {
                float cv = c4[k * DIM_ + j];
                a0[k] += cv * w0;
                a1[k] += cv * w1;
            }
        }
#pragma unroll
        for (int k = 0; k < 4; ++k) {
            cfin[((size_t)set * 4 + k) * DIM_ + tid] = a0[k];
            cfin[((size_t)set * 4 + k) * DIM_ + tid + 256] = a1[k];
        }
        for (int k = 0; k < 4; ++k) {
            float pbs = 0.f;
            for (int j = tid; j < DIM_; j += 256) pbs += cvt(pb[j]) * c4[k * DIM_ + j];
            red[tid] = pbs;
            __syncthreads();
            for (int o = 128; o >= 1; o >>= 1) {
                if (tid < o) red[tid] += red[tid + o];
                __syncthreads();
            }
            if (tid == 0) s0v[set * 4 + k] = red[0];
            __syncthreads();
        }
    } else {
        for (int p = tid; p < 4 * DIM_; p += 256) cfin[(size_t)set * 4 * DIM_ + p] = c4[p];
        if (tid < 4) s0v[set * 4 + tid] = 0.f;
    }
}

// ---------------- final: scores -> softmax -> weighted sum of normalized rows ----------------
template <typename T>
__global__ void final_kernel(const int* flag, const T* probes, const T* gallery,
                             const int* plen, const int* glen,
                             const float* cfin, const float* s0v, T* dout) {
    if (*flag != IsBf16<T>::v) return;
    int set = blockIdx.x, tid = threadIdx.x;
    bool probe = set < NPROBE;
    int L = probe ? LPR : LGA;
    const T* feat = probe ? probes + (size_t)set * L * DIM_
                          : gallery + (size_t)(set - NPROBE) * L * DIM_;
    int len = probe ? plen[set] : glen[set - NPROBE];
    int len_eff = min(max(len, 1), L);

    __shared__ float ctxf[4 * DIM_];
    __shared__ float coef[LGA * 4];
    __shared__ float invn[LGA];
    for (int p = tid; p < 4 * DIM_; p += 256) ctxf[p] = cfin[(size_t)set * 4 * DIM_ + p];
    __syncthreads();

    int wave = tid >> 6, lane = tid & 63;
    for (int l = wave; l < len_eff; l += 4) {
        const T* row = feat + (size_t)l * DIM_;
        float sq = 0, d0 = 0, d1 = 0, d2 = 0, d3 = 0;
#pragma unroll
        for (int j = 0; j < 8; ++j) {
            int dd = lane + 64 * j;
            float x = cvt(row[dd]);
            sq += x * x;
            d0 += x * ctxf[dd];
            d1 += x * ctxf[DIM_ + dd];
            d2 += x * ctxf[2 * DIM_ + dd];
            d3 += x * ctxf[3 * DIM_ + dd];
        }
#pragma unroll
        for (int off = 32; off >= 1; off >>= 1) {
            sq += __shfl_xor(sq, off, 64);
            d0 += __shfl_xor(d0, off, 64);
            d1 += __shfl_xor(d1, off, 64);
            d2 += __shfl_xor(d2, off, 64);
            d3 += __shfl_xor(d3, off, 64);
        }
        if (lane == 0) {
            invn[l] = 1.0f / fmaxf(sqrtf(sq), 1e-12f);
            coef[l * 4 + 0] = d0 + s0v[set * 4 + 0];
            coef[l * 4 + 1] = d1 + s0v[set * 4 + 1];
            coef[l * 4 + 2] = d2 + s0v[set * 4 + 2];
            coef[l * 4 + 3] = d3 + s0v[set * 4 + 3];
        }
    }
    __syncthreads();
    {   // one wave per slot k: softmax over valid rows, fold in 1/||feat_l||
        int k = wave;
        float m = -3e38f;
        for (int l = lane; l < len_eff; l += 64) m = fmaxf(m, coef[l * 4 + k]);
#pragma unroll
        for (int off = 32; off >= 1; off >>= 1) m = fmaxf(m, __shfl_xor(m, off, 64));
        float se = 0.f;
        for (int l = lane; l < len_eff; l += 64) se += __expf(coef[l * 4 + k] - m);
#pragma unroll
        for (int off = 32; off >= 1; off >>= 1) se += __shfl_xor(se, off, 64);
        float invs = 1.0f / se;
        for (int l = lane; l < len_eff; l += 64)
            coef[l * 4 + k] = __expf(coef[l * 4 + k] - m) * invs * invn[l];
    }
    __syncthreads();

    float a0[4] = {0, 0, 0, 0}, a1[4] = {0, 0, 0, 0};
    for (int l = 0; l < len_eff; ++l) {
        const T* row = feat + (size_t)l * DIM_;
        float f0 = cvt(row[tid]);
        float f1 = cvt(row[tid + 256]);
#pragma unroll
        for (int k = 0; k < 4; ++k) {
            float c = coef[l * 4 + k];
            a0[k] += f0 * c;
            a1[k] += f1 * c;
        }
    }
    size_t ob = probe ? O_OUT1 + (size_t)set * 4 * DIM_
                      : O_OUT3 + (size_t)(set - NPROBE) * 4 * DIM_;
#pragma unroll
    for (int k = 0; k < 4; ++k) {
        stor(dout + ob + k * DIM_ + tid, a0[k]);
        stor(dout + ob + k * DIM_ + tid + 256, a1[k]);
    }
}

template <typename T>
static void launch_path(void* const* d_in, void* d_out, float* wsf, int* flag,
                        hipStream_t stream) {
    const T* probes  = (const T*)d_in[0];
    const T* gallery = (const T*)d_in[1];
    const int* plen  = (const int*)d_in[2];
    const int* glen  = (const int*)d_in[3];
    const T* pp = (const T*)d_in[4];
    const T* pg = (const T*)d_in[5];
    const T* tW = (const T*)d_in[6];
    const T* tb = (const T*)d_in[7];
    const T* pW = (const T*)d_in[8];
    const T* pb = (const T*)d_in[9];
    const T* w1 = (const T*)d_in[10];
    const T* b1 = (const T*)d_in[11];
    const T* w2 = (const T*)d_in[12];
    const T* b2 = (const T*)d_in[13];
    const T* w3 = (const T*)d_in[14];
    const T* b3 = (const T*)d_in[15];
    T* dout = (T*)d_out;

    proxies_kernel<T><<<1, 256, 0, stream>>>(flag, pp, pg, tW, tb, wsf, dout);
    stats_kernel<T><<<NSETS, 256, 0, stream>>>(flag, probes, gallery, plen, glen, tW,
                                               wsf + OFF_TPP, wsf + OFF_TPG,
                                               wsf + OFF_MEAN, wsf + OFF_VAR,
                                               (int*)(wsf + OFF_IDX));
    mlp_kernel<T, 1><<<dim3(3, 16, KALL), 256, 0, stream>>>(
        flag, w1, b1, nullptr, wsf + OFF_MEAN, wsf + OFF_VAR, pp, pg,
        wsf + OFF_H1, 1024, 1536);
    mlp_kernel<T, 0><<<dim3(3, 16, KALL), 256, 0, stream>>>(
        flag, w2, b2, wsf + OFF_H1, nullptr, nullptr, pp, pg,
        wsf + OFF_H2, 1024, 1024);
    mlp_kernel<T, 0><<<dim3(3, 8, KALL), 256, 0, stream>>>(
        flag, w3, b3, wsf + OFF_H2, nullptr, nullptr, pp, pg,
        wsf + OFF_CTX, 512, 1024);
    ctx_kernel<T><<<NSETS, 256, 0, stream>>>(flag, wsf + OFF_CTX,
                                             (const int*)(wsf + OFF_IDX), pW, pb,
                                             wsf + OFF_CFIN, wsf + OFF_S0);
    final_kernel<T><<<NSETS, 256, 0, stream>>>(flag, probes, gallery, plen, glen,
                                               wsf + OFF_CFIN, wsf + OFF_S0, dout);
}

}  // namespace

extern "C" void kernel_launch(void* const* d_in, const int* in_sizes, int n_in,
                              void* d_out, int out_size, void* d_ws, size_t ws_size,
                              hipStream_t stream) {
    if (ws_size < WS_BYTES) return;  // refuse to corrupt memory; fails loudly
    float* wsf = (float*)d_ws;
    int* flag = (int*)d_ws;
    detect_kernel<<<1, 64, 0, stream>>>((const unsigned int*)d_in[8], flag);
    launch_path<float>(d_in, d_out, wsf, flag, stream);
    launch_path<__hip_bfloat16>(d_in, d_out, wsf, flag, stream);
}

// Round 2
// 757.778 us; speedup vs baseline: 1.4561x; 1.4561x over previous
//
#include <hip/hip_runtime.h>
#include <hip/hip_bf16.h>

namespace {

using us = unsigned short;
typedef __attribute__((ext_vector_type(8))) short bf16x8;
typedef __attribute__((ext_vector_type(4))) float f32x4;
typedef __attribute__((ext_vector_type(4))) unsigned short us4;
typedef __attribute__((ext_vector_type(4))) unsigned int u32x4;

constexpr int DIM_ = 512, KALL = 11, DOM = 10, NPROBE = 128, NSETS = 192;
constexpr int LPR = 256, LGA = 512;

// output offsets (elements)
constexpr size_t O_OUT1 = 0;
constexpr size_t O_OUT2 = (size_t)NPROBE * 4 * DIM_;
constexpr size_t O_OUT3 = O_OUT2 + KALL * DOM;
constexpr size_t O_OUT4 = O_OUT3 + (size_t)64 * 4 * DIM_;

// workspace offsets (floats). flag int at [0].
constexpr size_t F_S0   = 16;        // 768 f
constexpr size_t F_IDX  = 800;       // 768 int
constexpr size_t F_TP   = 1600;      // 2*128 f (normalized proxy transforms)
constexpr int    PSTR   = 1040;
constexpr size_t F_PART = 2048;                       // 768 * PSTR f
constexpr size_t F_SUMM = F_PART + 768 * (size_t)PSTR;  // bf16 [192][1024] = 98304 f
constexpr size_t F_H1   = F_SUMM + 98304;             // bf16 [11][192][1024] = 1081344 f
constexpr size_t F_H2   = F_H1 + 1081344;
constexpr size_t F_CTX  = F_H2 + 1081344;             // bf16 [11][192][512] = 540672 f
constexpr size_t F_CFIN = F_CTX + 540672;             // f32 [192][4][512]
constexpr size_t WS_FLOATS = F_CFIN + 393216;
constexpr size_t WS_BYTES = WS_FLOATS * 4;

__device__ __forceinline__ float b2f(us u) { return __uint_as_float(((unsigned)u) << 16); }
__device__ __forceinline__ us f2b(float x) {
    unsigned u = __float_as_uint(x);
    u += 0x7FFF + ((u >> 16) & 1);
    return (us)(u >> 16);
}
__device__ __forceinline__ float ldT(const float* p) { return *p; }
__device__ __forceinline__ float ldT(const us* p) { return b2f(*p); }
__device__ __forceinline__ void stT(float* p, float v) { *p = v; }
__device__ __forceinline__ void stT(us* p, float v) { *p = f2b(v); }

__device__ __forceinline__ bf16x8 loadA(const us* p) { return *(const bf16x8*)p; }
__device__ __forceinline__ bf16x8 loadA(const float* p) {
    f32x4 a = *(const f32x4*)p, b = *(const f32x4*)(p + 4);
    bf16x8 r;
#pragma unroll
    for (int j = 0; j < 4; ++j) { r[j] = (short)f2b(a[j]); r[4 + j] = (short)f2b(b[j]); }
    return r;
}

// ---------------- dtype detector ----------------
__global__ void detect_kernel(const unsigned int* probeW_bits, int* flag) {
    if (threadIdx.x == 0) *flag = (probeW_bits[0] == 0x3F800000u) ? 0 : 1;
}

// ---------------- proxies: out2/out4 + normalized tp ----------------
template <typename T>
__device__ void proxies_body(const T* pp, const T* pg, const T* tW, const T* tb,
                             float* wsf, T* dout) {
    int b = blockIdx.x;             // 22 blocks
    int fam = b / KALL, i = b % KALL;
    int lane = threadIdx.x;         // 64
    const T* src = fam ? pg : pp;
    float t[DOM];
#pragma unroll
    for (int r = 0; r < DOM; ++r) t[r] = 0.f;
    for (int d = lane; d < DIM_; d += 64) {
        float x = ldT(src + (size_t)i * DIM_ + d);
#pragma unroll
        for (int r = 0; r < DOM; ++r) t[r] += x * ldT(tW + (size_t)r * DIM_ + d);
    }
#pragma unroll
    for (int off = 32; off >= 1; off >>= 1)
#pragma unroll
        for (int r = 0; r < DOM; ++r) t[r] += __shfl_xor(t[r], off, 64);
#pragma unroll
    for (int r = 0; r < DOM; ++r) t[r] += ldT(tb + r);
    float nn = 0.f;
#pragma unroll
    for (int r = 0; r < DOM; ++r) nn += t[r] * t[r];
    float inv = 1.0f / fmaxf(sqrtf(nn), 1e-12f);
    if (lane < DOM) {
        size_t base = fam ? O_OUT4 : O_OUT2;
        stT(dout + base + i * DOM + lane, t[lane]);
        wsf[F_TP + fam * 128 + i * DOM + lane] = t[lane] * inv;
    }
}
__global__ void proxies_kernel(const int* flag, const void* pp, const void* pg,
                               const void* tW, const void* tb, float* wsf, void* dout) {
    if (*flag)
        proxies_body<us>((const us*)pp, (const us*)pg, (const us*)tW, (const us*)tb, wsf, (us*)dout);
    else
        proxies_body<float>((const float*)pp, (const float*)pg, (const float*)tW, (const float*)tb, wsf, (float*)dout);
}

// ---------------- per-set stats, chunked: partial gsim / sum / sumsq ----------------
template <typename T>
__global__ __launch_bounds__(512) void stats_kernel(const int* flag, const T* probes,
        const T* gallery, const int* plen, const int* glen, const T* tW, float* wsf) {
    if (*flag != (int)(sizeof(T) == 2)) return;
    int bx = blockIdx.x, set = bx >> 2, c = bx & 3;
    bool probe = set < NPROBE;
    int L = probe ? LPR : LGA;
    const T* feat = probe ? probes + (size_t)set * L * DIM_
                          : gallery + (size_t)(set - NPROBE) * L * DIM_;
    int len = probe ? plen[set] : glen[set - NPROBE];
    int len_eff = min(max(len, 1), L);
    int r0 = c * (L / 4), r1 = min(r0 + L / 4, len_eff);

    __shared__ float tpl[KALL * DOM];
    __shared__ float psum[DIM_], psq[DIM_], gs[KALL];
    int tid = threadIdx.x;
    const float* tp = wsf + F_TP + (probe ? 0 : 128);
    if (tid < KALL * DOM) tpl[tid] = tp[tid];
    if (tid < KALL) gs[tid] = 0.f;
    if (tid < DIM_) { psum[tid] = 0.f; psq[tid] = 0.f; }
    __syncthreads();
    int w = tid >> 6, lane = tid & 63;
    float asum[8] = {0,0,0,0,0,0,0,0}, asq[8] = {0,0,0,0,0,0,0,0}, gacc = 0.f;

    if constexpr (sizeof(T) == 2) {
        unsigned wp[DOM][4];
#pragma unroll
        for (int r = 0; r < DOM; ++r)
#pragma unroll
            for (int q = 0; q < 4; ++q)
                wp[r][q] = *(const unsigned*)(tW + (size_t)r * DIM_ + lane * 8 + q * 2);
        for (int l = r0 + w; l < r1; l += 8) {
            u32x4 raw = *(const u32x4*)(feat + (size_t)l * DIM_ + lane * 8);
            float f[8];
#pragma unroll
            for (int q = 0; q < 4; ++q) {
                f[2*q]   = __uint_as_float(raw[q] << 16);
                f[2*q+1] = __uint_as_float(raw[q] & 0xFFFF0000u);
            }
            float t[DOM];
#pragma unroll
            for (int r = 0; r < DOM; ++r) {
                float s = 0.f;
#pragma unroll
                for (int q = 0; q < 4; ++q) {
                    unsigned u = wp[r][q];
                    s += f[2*q] * __uint_as_float(u << 16);
                    s += f[2*q+1] * __uint_as_float(u & 0xFFFF0000u);
                }
                t[r] = s;
            }
#pragma unroll
            for (int j = 0; j < 8; ++j) { asum[j] += f[j]; asq[j] += f[j] * f[j]; }
#pragma unroll
            for (int off = 32; off >= 1; off >>= 1)
#pragma unroll
                for (int r = 0; r < DOM; ++r) t[r] += __shfl_xor(t[r], off, 64);
            float nn = 0.f;
#pragma unroll
            for (int r = 0; r < DOM; ++r) nn += t[r] * t[r];
            float inv = 1.0f / fmaxf(sqrtf(nn), 1e-12f);
            if (lane < KALL) {
                float s = 0.f;
#pragma unroll
                for (int r = 0; r < DOM; ++r) s += t[r] * tpl[lane * DOM + r];
                gacc += s * inv;
            }
        }
    } else {
        float wreg[DOM][8];
#pragma unroll
        for (int r = 0; r < DOM; ++r)
#pragma unroll
            for (int j = 0; j < 8; ++j) wreg[r][j] = ldT(tW + (size_t)r * DIM_ + lane * 8 + j);
        for (int l = r0 + w; l < r1; l += 8) {
            const T* rp = feat + (size_t)l * DIM_ + lane * 8;
            f32x4 ra = *(const f32x4*)rp, rb = *(const f32x4*)(rp + 4);
            float f[8];
#pragma unroll
            for (int j = 0; j < 4; ++j) { f[j] = ra[j]; f[4+j] = rb[j]; }
            float t[DOM];
#pragma unroll
            for (int r = 0; r < DOM; ++r) {
                float s = 0.f;
#pragma unroll
                for (int j = 0; j < 8; ++j) s += f[j] * wreg[r][j];
                t[r] = s;
            }
#pragma unroll
            for (int j = 0; j < 8; ++j) { asum[j] += f[j]; asq[j] += f[j] * f[j]; }
#pragma unroll
            for (int off = 32; off >= 1; off >>= 1)
#pragma unroll
                for (int r = 0; r < DOM; ++r) t[r] += __shfl_xor(t[r], off, 64);
            float nn = 0.f;
#pragma unroll
            for (int r = 0; r < DOM; ++r) nn += t[r] * t[r];
            float inv = 1.0f / fmaxf(sqrtf(nn), 1e-12f);
            if (lane < KALL) {
                float s = 0.f;
#pragma unroll
                for (int r = 0; r < DOM; ++r) s += t[r] * tpl[lane * DOM + r];
                gacc += s * inv;
            }
        }
    }
    if (lane < KALL) atomicAdd(&gs[lane], gacc);
#pragma unroll
    for (int j = 0; j < 8; ++j) {
        atomicAdd(&psum[lane * 8 + j], asum[j]);
        atomicAdd(&psq[lane * 8 + j], asq[j]);
    }
    __syncthreads();
    float* P = wsf + F_PART + (size_t)bx * PSTR;
    if (tid < DIM_) { P[tid] = psum[tid]; P[DIM_ + tid] = psq[tid]; }
    if (tid < KALL) P[1024 + tid] = gs[tid];
}

// ---------------- finalize stats: SUMM (bf16) + top4 ----------------
__global__ void statsfin_kernel(const int* plen, const int* glen, float* wsf) {
    int set = blockIdx.x, tid = threadIdx.x;
    bool probe = set < NPROBE;
    int len = probe ? plen[set] : glen[set - NPROBE];
    float lp = (float)max(len, 1);
    const float* P = wsf + F_PART + (size_t)set * 4 * PSTR;
    us* SUMM = (us*)(wsf + F_SUMM);
    for (int d = tid; d < DIM_; d += 256) {
        float s = P[d] + P[PSTR + d] + P[2 * PSTR + d] + P[3 * PSTR + d];
        float q = P[DIM_ + d] + P[PSTR + DIM_ + d] + P[2 * PSTR + DIM_ + d] + P[3 * PSTR + DIM_ + d];
        float m = s / lp;
        float v = q / lp - m * m;
        SUMM[(size_t)set * 1024 + d] = f2b(m);
        SUMM[(size_t)set * 1024 + DIM_ + d] = f2b(v);
    }
    if (tid == 0) {
        float g[KALL];
        for (int i = 0; i < KALL; ++i)
            g[i] = P[1024 + i] + P[PSTR + 1024 + i] + P[2 * PSTR + 1024 + i] + P[3 * PSTR + 1024 + i];
        int* idx4 = (int*)(wsf + F_IDX);
        for (int kk = 0; kk < 4; ++kk) {
            int bi = 0; float bv = g[0];
            for (int i = 1; i < KALL; ++i)
                if (g[i] > bv) { bv = g[i]; bi = i; }
            idx4[set * 4 + kk] = bi;
            g[bi] = -3e38f;
        }
    }
}

// ---------------- MFMA batched expert MLP layer ----------------
// Y[e][s][m] = leaky( sum_k W[e][m][k] * X[e][s][k] + b[e][m] ), all bf16 I/O for X,Y.
template <typename T, int M, int K, int L1>
__device__ void mlp_body(const T* W, const T* bias, const T* pp, const T* pg,
                         const us* X, us* Y) {
    int e = blockIdx.y, mt = blockIdx.x;
    int tid = threadIdx.x, w = tid >> 6, lane = tid & 63;
    int lm = lane & 15, quad = lane >> 4, kq = quad * 8;
    const int RS = L1 ? 1024 : K;
    const T* Ap = W + ((size_t)e * M + mt * 64 + w * 16 + lm) * K + kq;
    const us* Xp = L1 ? X + (size_t)lm * RS + kq
                      : X + ((size_t)e * NSETS + lm) * RS + kq;
    f32x4 acc[12];
#pragma unroll
    for (int nt = 0; nt < 12; ++nt) acc[nt] = (f32x4){0.f, 0.f, 0.f, 0.f};

    const int KX = L1 ? 1024 : K;
#pragma unroll 4
    for (int kc = 0; kc < KX; kc += 32) {
        bf16x8 a = loadA(Ap + kc);
#pragma unroll
        for (int nt = 0; nt < 12; ++nt) {
            bf16x8 b = *(const bf16x8*)(Xp + kc + (size_t)nt * 16 * RS);
            acc[nt] = __builtin_amdgcn_mfma_f32_16x16x32_bf16(a, b, acc[nt], 0, 0, 0);
        }
    }
    if (L1) {
#pragma unroll 4
        for (int kc = 1024; kc < 1536; kc += 32) {
            bf16x8 a = loadA(Ap + kc);
            bf16x8 bp = loadA(pp + (size_t)e * DIM_ + (kc - 1024) + kq);
            bf16x8 bg = loadA(pg + (size_t)e * DIM_ + (kc - 1024) + kq);
#pragma unroll
            for (int nt = 0; nt < 12; ++nt)
                acc[nt] = __builtin_amdgcn_mfma_f32_16x16x32_bf16(a, nt < 8 ? bp : bg, acc[nt], 0, 0, 0);
        }
    }
    int m0 = mt * 64 + w * 16 + quad * 4;
    float bv[4];
#pragma unroll
    for (int r = 0; r < 4; ++r) bv[r] = ldT(bias + (size_t)e * M + m0 + r);
#pragma unroll
    for (int nt = 0; nt < 12; ++nt) {
        int s = nt * 16 + lm;
        us4 pk;
#pragma unroll
        for (int r = 0; r < 4; ++r) {
            float v = acc[nt][r] + bv[r];
            v = v > 0.f ? v : 0.01f * v;
            pk[r] = f2b(v);
        }
        *(us4*)(Y + ((size_t)e * NSETS + s) * M + m0) = pk;
    }
}
template <int M, int K, int L1>
__global__ void mlp_kernel(const int* flag, const void* W, const void* bias,
                           const void* pp, const void* pg, const us* X, us* Y) {
    if (*flag)
        mlp_body<us, M, K, L1>((const us*)W, (const us*)bias, (const us*)pp, (const us*)pg, X, Y);
    else
        mlp_body<float, M, K, L1>((const float*)W, (const float*)bias, (const float*)pp, (const float*)pg, X, Y);
}

// ---------------- gather selected ctx; fold probe_W/probe_b ----------------
template <typename T>
__device__ void gather_body(const us* CTX, const T* pW, const T* pb, float* wsf) {
    int set = blockIdx.x, tid = threadIdx.x;
    bool probe = set < NPROBE;
    __shared__ float c4[4 * DIM_];
    __shared__ int eid[4];
    const int* idx4 = (const int*)(wsf + F_IDX);
    if (tid < 4) eid[tid] = idx4[set * 4 + tid];
    __syncthreads();
    for (int p = tid; p < 4 * DIM_; p += 1024) {
        int k = p >> 9, d = p & 511;
        c4[p] = b2f(CTX[((size_t)eid[k] * NSETS + set) * DIM_ + d]);
    }
    __syncthreads();
    int w = tid >> 6, lane = tid & 63;
    if (w < 4) {
        float pbs = 0.f;
        for (int d = lane; d < DIM_; d += 64) pbs += ldT(pb + d) * c4[w * DIM_ + d];
#pragma unroll
        for (int off = 32; off >= 1; off >>= 1) pbs += __shfl_xor(pbs, off, 64);
        if (lane == 0) wsf[F_S0 + set * 4 + w] = probe ? pbs : 0.f;
    }
    float* cf = wsf + F_CFIN + (size_t)set * 4 * DIM_;
    if (probe) {
        int d = tid & 511, kk = tid >> 9;   // kk in {0,1}; handles slots kk and kk+2
        float a0 = 0.f, a1 = 0.f;
        for (int j = 0; j < DIM_; ++j) {
            float wv = ldT(pW + (size_t)j * DIM_ + d);
            a0 += c4[kk * DIM_ + j] * wv;
            a1 += c4[(kk + 2) * DIM_ + j] * wv;
        }
        cf[kk * DIM_ + d] = a0;
        cf[(kk + 2) * DIM_ + d] = a1;
    } else {
        for (int p = tid; p < 4 * DIM_; p += 1024) cf[p] = c4[p];
    }
}
__global__ void gather_kernel(const int* flag, const us* CTX, const void* pW,
                              const void* pb, float* wsf) {
    if (*flag) gather_body<us>(CTX, (const us*)pW, (const us*)pb, wsf);
    else gather_body<float>(CTX, (const float*)pW, (const float*)pb, wsf);
}

// ---------------- final: scores -> softmax -> weighted sum of normalized rows ----------------
template <typename T>
__device__ void final_body(const T* probes, const T* gallery, const int* plen,
                           const int* glen, const float* wsf, T* dout) {
    int set = blockIdx.x, tid = threadIdx.x;
    bool probe = set < NPROBE;
    int L = probe ? LPR : LGA;
    const T* feat = probe ? probes + (size_t)set * L * DIM_
                          : gallery + (size_t)(set - NPROBE) * L * DIM_;
    int len = probe ? plen[set] : glen[set - NPROBE];
    int len_eff = min(max(len, 1), L);

    __shared__ float ctxf[4 * DIM_];
    __shared__ float coef[LGA * 4];
    __shared__ float invn[LGA];
    __shared__ float part[DIM_ * 4];
    __shared__ float s0s[4];
    const float* cf = wsf + F_CFIN + (size_t)set * 4 * DIM_;
    for (int p = tid; p < 4 * DIM_; p += 1024) ctxf[p] = cf[p];
    if (tid < 4) s0s[tid] = wsf[F_S0 + set * 4 + tid];
    __syncthreads();

    int w = tid >> 6, lane = tid & 63;
    for (int l = w; l < len_eff; l += 16) {
        float f[8];
        if constexpr (sizeof(T) == 2) {
            u32x4 raw = *(const u32x4*)(feat + (size_t)l * DIM_ + lane * 8);
#pragma unroll
            for (int q = 0; q < 4; ++q) {
                f[2*q]   = __uint_as_float(raw[q] << 16);
                f[2*q+1] = __uint_as_float(raw[q] & 0xFFFF0000u);
            }
        } else {
            const T* rp = feat + (size_t)l * DIM_ + lane * 8;
            f32x4 ra = *(const f32x4*)rp, rb = *(const f32x4*)(rp + 4);
#pragma unroll
            for (int j = 0; j < 4; ++j) { f[j] = ra[j]; f[4+j] = rb[j]; }
        }
        float sq = 0.f, d0 = 0.f, d1 = 0.f, d2 = 0.f, d3 = 0.f;
#pragma unroll
        for (int j = 0; j < 8; ++j) {
            float x = f[j];
            int dd = lane * 8 + j;
            sq += x * x;
            d0 += x * ctxf[dd];
            d1 += x * ctxf[DIM_ + dd];
            d2 += x * ctxf[2 * DIM_ + dd];
            d3 += x * ctxf[3 * DIM_ + dd];
        }
#pragma unroll
        for (int off = 32; off >= 1; off >>= 1) {
            sq += __shfl_xor(sq, off, 64);
            d0 += __shfl_xor(d0, off, 64);
            d1 += __shfl_xor(d1, off, 64);
            d2 += __shfl_xor(d2, off, 64);
            d3 += __shfl_xor(d3, off, 64);
        }
        if (lane == 0) {
            invn[l] = 1.0f / fmaxf(sqrtf(sq), 1e-12f);
            coef[l * 4 + 0] = d0 + s0s[0];
            coef[l * 4 + 1] = d1 + s0s[1];
            coef[l * 4 + 2] = d2 + s0s[2];
            coef[l * 4 + 3] = d3 + s0s[3];
        }
    }
    __syncthreads();
    if (w < 4) {
        int k = w;
        float mm = -3e38f;
        for (int l = lane; l < len_eff; l += 64) mm = fmaxf(mm, coef[l * 4 + k]);
#pragma unroll
        for (int off = 32; off >= 1; off >>= 1) mm = fmaxf(mm, __shfl_xor(mm, off, 64));
        float se = 0.f;
        for (int l = lane; l < len_eff; l += 64) se += __expf(coef[l * 4 + k] - mm);
#pragma unroll
        for (int off = 32; off >= 1; off >>= 1) se += __shfl_xor(se, off, 64);
        float invs = 1.0f / se;
        for (int l = lane; l < len_eff; l += 64)
            coef[l * 4 + k] = __expf(coef[l * 4 + k] - mm) * invs * invn[l];
    }
    __syncthreads();

    int d = tid & 511, half = tid >> 9;
    float ac[4] = {0.f, 0.f, 0.f, 0.f};
    for (int l = half; l < len_eff; l += 2) {
        float x = ldT(feat + (size_t)l * DIM_ + d);
        f32x4 cc = *(const f32x4*)&coef[l * 4];
        ac[0] += x * cc[0]; ac[1] += x * cc[1]; ac[2] += x * cc[2]; ac[3] += x * cc[3];
    }
    if (half == 1) {
#pragma unroll
        for (int k = 0; k < 4; ++k) part[d * 4 + k] = ac[k];
    }
    __syncthreads();
    if (half == 0) {
        size_t ob = probe ? O_OUT1 + (size_t)set * 4 * DIM_
                          : O_OUT3 + (size_t)(set - NPROBE) * 4 * DIM_;
#pragma unroll
        for (int k = 0; k < 4; ++k) stT(dout + ob + k * DIM_ + d, ac[k] + part[d * 4 + k]);
    }
}
__global__ void final_kernel(const int* flag, const void* probes, const void* gallery,
                             const int* plen, const int* glen, const float* wsf, void* dout) {
    if (*flag)
        final_body<us>((const us*)probes, (const us*)gallery, plen, glen, wsf, (us*)dout);
    else
        final_body<float>((const float*)probes, (const float*)gallery, plen, glen, wsf, (float*)dout);
}

}  // namespace

extern "C" void kernel_launch(void* const* d_in, const int* in_sizes, int n_in,
                              void* d_out, int out_size, void* d_ws, size_t ws_size,
                              hipStream_t stream) {
    if (ws_size < WS_BYTES) return;
    float* wsf = (float*)d_ws;
    int* flag = (int*)d_ws;
    us* SUMM = (us*)(wsf + F_SUMM);
    us* H1 = (us*)(wsf + F_H1);
    us* H2 = (us*)(wsf + F_H2);
    us* CTXb = (us*)(wsf + F_CTX);
    const int* plen = (const int*)d_in[2];
    const int* glen = (const int*)d_in[3];

    detect_kernel<<<1, 64, 0, stream>>>((const unsigned int*)d_in[8], flag);
    proxies_kernel<<<22, 64, 0, stream>>>(flag, d_in[4], d_in[5], d_in[6], d_in[7], wsf, d_out);
    stats_kernel<float><<<NSETS * 4, 512, 0, stream>>>(flag, (const float*)d_in[0],
        (const float*)d_in[1], plen, glen, (const float*)d_in[6], wsf);
    stats_kernel<us><<<NSETS * 4, 512, 0, stream>>>(flag, (const us*)d_in[0],
        (const us*)d_in[1], plen, glen, (const us*)d_in[6], wsf);
    statsfin_kernel<<<NSETS, 256, 0, stream>>>(plen, glen, wsf);
    mlp_kernel<1024, 1536, 1><<<dim3(16, KALL), 256, 0, stream>>>(
        flag, d_in[10], d_in[11], d_in[4], d_in[5], SUMM, H1);
    mlp_kernel<1024, 1024, 0><<<dim3(16, KALL), 256, 0, stream>>>(
        flag, d_in[12], d_in[13], d_in[4], d_in[5], H1, H2);
    mlp_kernel<512, 1024, 0><<<dim3(8, KALL), 256, 0, stream>>>(
        flag, d_in[14], d_in[15], d_in[4], d_in[5], H2, CTXb);
    gather_kernel<<<NSETS, 1024, 0, stream>>>(flag, CTXb, d_in[8], d_in[9], wsf);
    final_kernel<<<NSETS, 1024, 0, stream>>>(flag, d_in[0], d_in[1], plen, glen, wsf, d_out);
}

// Round 3
// 635.505 us; speedup vs baseline: 1.7363x; 1.1924x over previous
//
#include <hip/hip_runtime.h>
#include <hip/hip_bf16.h>

namespace {

using us = unsigned short;
typedef __attribute__((ext_vector_type(8))) short bf16x8;
typedef __attribute__((ext_vector_type(4))) float f32x4;
typedef __attribute__((ext_vector_type(4))) unsigned short us4;
typedef __attribute__((ext_vector_type(4))) unsigned int u32x4;

constexpr int DIM_ = 512, KALL = 11, DOM = 10, NPROBE = 128, NSETS = 192;
constexpr int LPR = 256, LGA = 512;

// output offsets (elements)
constexpr size_t O_OUT1 = 0;
constexpr size_t O_OUT2 = (size_t)NPROBE * 4 * DIM_;
constexpr size_t O_OUT3 = O_OUT2 + KALL * DOM;
constexpr size_t O_OUT4 = O_OUT3 + (size_t)64 * 4 * DIM_;

// workspace offsets (floats). flag int at [0]. Regions reused across phases:
//  F_PART (stats partials) -> later F_WCOEF+F_INVN (score phase)
//  F_H1 -> later F_CTXW ;  F_H2 (+F_CTX tail) -> later F_ACC
constexpr size_t F_TP   = 64;       // 256 f
constexpr size_t F_IDX  = 320;      // 768 int
constexpr size_t F_S0A  = 1600;     // 2112 f
constexpr int    PSTR   = 1040;
constexpr size_t F_PART = 4096;                 // 768*1040 = 798720
constexpr size_t F_WCOEF= 4096;                 // 192*512*4 = 393216 (alias PART)
constexpr size_t F_INVN = 397312;               // 192*512 = 98304   (alias PART)
constexpr size_t F_SUMM = 802816;               // bf16 [192][1024] = 98304 f
constexpr size_t F_H1   = 901120;               // bf16 [11][192][1024] = 1081344 f
constexpr size_t F_CTXW = 901120;               // bf16 [11][192][512] (alias H1)
constexpr size_t F_H2   = 1982464;              // 1081344 f
constexpr size_t F_ACC  = 1982464;              // f32 768*2048 = 1572864 (alias H2+CTX)
constexpr size_t F_CTX  = 3063808;              // bf16 [11][192][512] = 540672 f
constexpr size_t F_WT   = 3604480;              // bf16 [512][512] = 131072 f
constexpr size_t WS_FLOATS = 3735552;
constexpr size_t WS_BYTES = WS_FLOATS * 4;

__device__ __forceinline__ float b2f(us u) { return __uint_as_float(((unsigned)u) << 16); }
__device__ __forceinline__ us f2b(float x) {
    unsigned u = __float_as_uint(x);
    u += 0x7FFF + ((u >> 16) & 1);
    return (us)(u >> 16);
}
__device__ __forceinline__ float ldT(const float* p) { return *p; }
__device__ __forceinline__ float ldT(const us* p) { return b2f(*p); }
__device__ __forceinline__ void stT(float* p, float v) { *p = v; }
__device__ __forceinline__ void stT(us* p, float v) { *p = f2b(v); }

__device__ __forceinline__ bf16x8 loadA(const us* p) { return *(const bf16x8*)p; }
__device__ __forceinline__ bf16x8 loadA(const float* p) {
    f32x4 a = *(const f32x4*)p, b = *(const f32x4*)(p + 4);
    bf16x8 r;
#pragma unroll
    for (int j = 0; j < 4; ++j) { r[j] = (short)f2b(a[j]); r[4 + j] = (short)f2b(b[j]); }
    return r;
}

// ---------------- dtype detector ----------------
__global__ void detect_kernel(const unsigned int* probeW_bits, int* flag) {
    if (threadIdx.x == 0) *flag = (probeW_bits[0] == 0x3F800000u) ? 0 : 1;
}

// ---------------- proxies: out2/out4 + normalized tp ----------------
template <typename T>
__device__ void proxies_body(const T* pp, const T* pg, const T* tW, const T* tb,
                             float* wsf, T* dout) {
    int b = blockIdx.x;             // 22 blocks
    int fam = b / KALL, i = b % KALL;
    int lane = threadIdx.x;         // 64
    const T* src = fam ? pg : pp;
    float t[DOM];
#pragma unroll
    for (int r = 0; r < DOM; ++r) t[r] = 0.f;
    for (int d = lane; d < DIM_; d += 64) {
        float x = ldT(src + (size_t)i * DIM_ + d);
#pragma unroll
        for (int r = 0; r < DOM; ++r) t[r] += x * ldT(tW + (size_t)r * DIM_ + d);
    }
#pragma unroll
    for (int off = 32; off >= 1; off >>= 1)
#pragma unroll
        for (int r = 0; r < DOM; ++r) t[r] += __shfl_xor(t[r], off, 64);
#pragma unroll
    for (int r = 0; r < DOM; ++r) t[r] += ldT(tb + r);
    float nn = 0.f;
#pragma unroll
    for (int r = 0; r < DOM; ++r) nn += t[r] * t[r];
    float inv = 1.0f / fmaxf(sqrtf(nn), 1e-12f);
    if (lane < DOM) {
        size_t base = fam ? O_OUT4 : O_OUT2;
        stT(dout + base + i * DOM + lane, t[lane]);
        wsf[F_TP + fam * 128 + i * DOM + lane] = t[lane] * inv;
    }
}
__global__ void proxies_kernel(const int* flag, const void* pp, const void* pg,
                               const void* tW, const void* tb, float* wsf, void* dout) {
    if (*flag)
        proxies_body<us>((const us*)pp, (const us*)pg, (const us*)tW, (const us*)tb, wsf, (us*)dout);
    else
        proxies_body<float>((const float*)pp, (const float*)pg, (const float*)tW, (const float*)tb, wsf, (float*)dout);
}

// ---------------- per-set stats, chunked ----------------
template <typename T>
__global__ __launch_bounds__(1024) void stats_kernel(const int* flag, const T* probes,
        const T* gallery, const int* plen, const int* glen, const T* tW, float* wsf) {
    if (*flag != (int)(sizeof(T) == 2)) return;
    int bx = blockIdx.x, set = bx >> 2, c = bx & 3;
    bool probe = set < NPROBE;
    int L = probe ? LPR : LGA;
    const T* feat = probe ? probes + (size_t)set * L * DIM_
                          : gallery + (size_t)(set - NPROBE) * L * DIM_;
    int len = probe ? plen[set] : glen[set - NPROBE];
    int len_eff = min(max(len, 1), L);
    int r0 = c * (L / 4), r1 = min(r0 + L / 4, len_eff);

    __shared__ float tpl[KALL * DOM];
    __shared__ float psum[DIM_], psq[DIM_], gs[KALL];
    int tid = threadIdx.x;
    const float* tp = wsf + F_TP + (probe ? 0 : 128);
    if (tid < KALL * DOM) tpl[tid] = tp[tid];
    if (tid < KALL) gs[tid] = 0.f;
    if (tid < DIM_) { psum[tid] = 0.f; psq[tid] = 0.f; }
    __syncthreads();
    int w = tid >> 6, lane = tid & 63;
    float asum[8] = {0,0,0,0,0,0,0,0}, asq[8] = {0,0,0,0,0,0,0,0}, gacc = 0.f;

    if constexpr (sizeof(T) == 2) {
        unsigned wp[DOM][4];
#pragma unroll
        for (int r = 0; r < DOM; ++r)
#pragma unroll
            for (int q = 0; q < 4; ++q)
                wp[r][q] = *(const unsigned*)(tW + (size_t)r * DIM_ + lane * 8 + q * 2);
        for (int l = r0 + w; l < r1; l += 16) {
            u32x4 raw = *(const u32x4*)(feat + (size_t)l * DIM_ + lane * 8);
            float f[8];
#pragma unroll
            for (int q = 0; q < 4; ++q) {
                f[2*q]   = __uint_as_float(raw[q] << 16);
                f[2*q+1] = __uint_as_float(raw[q] & 0xFFFF0000u);
            }
            float t[DOM];
#pragma unroll
            for (int r = 0; r < DOM; ++r) {
                float s = 0.f;
#pragma unroll
                for (int q = 0; q < 4; ++q) {
                    unsigned u = wp[r][q];
                    s += f[2*q] * __uint_as_float(u << 16);
                    s += f[2*q+1] * __uint_as_float(u & 0xFFFF0000u);
                }
                t[r] = s;
            }
#pragma unroll
            for (int j = 0; j < 8; ++j) { asum[j] += f[j]; asq[j] += f[j] * f[j]; }
#pragma unroll
            for (int off = 32; off >= 1; off >>= 1)
#pragma unroll
                for (int r = 0; r < DOM; ++r) t[r] += __shfl_xor(t[r], off, 64);
            float nn = 0.f;
#pragma unroll
            for (int r = 0; r < DOM; ++r) nn += t[r] * t[r];
            float inv = 1.0f / fmaxf(sqrtf(nn), 1e-12f);
            if (lane < KALL) {
                float s = 0.f;
#pragma unroll
                for (int r = 0; r < DOM; ++r) s += t[r] * tpl[lane * DOM + r];
                gacc += s * inv;
            }
        }
    } else {
        float wreg[DOM][8];
#pragma unroll
        for (int r = 0; r < DOM; ++r)
#pragma unroll
            for (int j = 0; j < 8; ++j) wreg[r][j] = ldT(tW + (size_t)r * DIM_ + lane * 8 + j);
        for (int l = r0 + w; l < r1; l += 16) {
            const T* rp = feat + (size_t)l * DIM_ + lane * 8;
            f32x4 ra = *(const f32x4*)rp, rb = *(const f32x4*)(rp + 4);
            float f[8];
#pragma unroll
            for (int j = 0; j < 4; ++j) { f[j] = ra[j]; f[4+j] = rb[j]; }
            float t[DOM];
#pragma unroll
            for (int r = 0; r < DOM; ++r) {
                float s = 0.f;
#pragma unroll
                for (int j = 0; j < 8; ++j) s += f[j] * wreg[r][j];
                t[r] = s;
            }
#pragma unroll
            for (int j = 0; j < 8; ++j) { asum[j] += f[j]; asq[j] += f[j] * f[j]; }
#pragma unroll
            for (int off = 32; off >= 1; off >>= 1)
#pragma unroll
                for (int r = 0; r < DOM; ++r) t[r] += __shfl_xor(t[r], off, 64);
            float nn = 0.f;
#pragma unroll
            for (int r = 0; r < DOM; ++r) nn += t[r] * t[r];
            float inv = 1.0f / fmaxf(sqrtf(nn), 1e-12f);
            if (lane < KALL) {
                float s = 0.f;
#pragma unroll
                for (int r = 0; r < DOM; ++r) s += t[r] * tpl[lane * DOM + r];
                gacc += s * inv;
            }
        }
    }
    if (lane < KALL) atomicAdd(&gs[lane], gacc);
#pragma unroll
    for (int j = 0; j < 8; ++j) {
        atomicAdd(&psum[lane * 8 + j], asum[j]);
        atomicAdd(&psq[lane * 8 + j], asq[j]);
    }
    __syncthreads();
    float* P = wsf + F_PART + (size_t)bx * PSTR;
    if (tid < DIM_) { P[tid] = psum[tid]; P[DIM_ + tid] = psq[tid]; }
    if (tid < KALL) P[1024 + tid] = gs[tid];
}

// ---------------- finalize stats: SUMM (bf16) + top4 ----------------
__global__ void statsfin_kernel(const int* plen, const int* glen, float* wsf) {
    int set = blockIdx.x, tid = threadIdx.x;
    bool probe = set < NPROBE;
    int len = probe ? plen[set] : glen[set - NPROBE];
    float lp = (float)max(len, 1);
    const float* P = wsf + F_PART + (size_t)set * 4 * PSTR;
    us* SUMM = (us*)(wsf + F_SUMM);
    for (int d = tid; d < DIM_; d += 256) {
        float s = P[d] + P[PSTR + d] + P[2 * PSTR + d] + P[3 * PSTR + d];
        float q = P[DIM_ + d] + P[PSTR + DIM_ + d] + P[2 * PSTR + DIM_ + d] + P[3 * PSTR + DIM_ + d];
        float m = s / lp;
        float v = q / lp - m * m;
        SUMM[(size_t)set * 1024 + d] = f2b(m);
        SUMM[(size_t)set * 1024 + DIM_ + d] = f2b(v);
    }
    if (tid == 0) {
        float g[KALL];
        for (int i = 0; i < KALL; ++i)
            g[i] = P[1024 + i] + P[PSTR + 1024 + i] + P[2 * PSTR + 1024 + i] + P[3 * PSTR + 1024 + i];
        int* idx4 = (int*)(wsf + F_IDX);
        for (int kk = 0; kk < 4; ++kk) {
            int bi = 0; float bv = g[0];
            for (int i = 1; i < KALL; ++i)
                if (g[i] > bv) { bv = g[i]; bi = i; }
            idx4[set * 4 + kk] = bi;
            g[bi] = -3e38f;
        }
    }
}

// ---------------- W transpose -> WT bf16 [j][d] ----------------
template <typename T>
__device__ void wt_body(const T* W, us* WT) {
    __shared__ us t[64][65];
    int bi = blockIdx.y * 64, bj = blockIdx.x * 64, tid = threadIdx.x;
    for (int i = tid; i < 4096; i += 256) {
        int r = i >> 6, cc = i & 63;
        t[r][cc] = (sizeof(T) == 2) ? (us)__builtin_bit_cast(short, (short)((const us*)W)[(size_t)(bi + r) * DIM_ + bj + cc])
                                    : f2b(ldT(W + (size_t)(bi + r) * DIM_ + bj + cc));
    }
    __syncthreads();
    for (int i = tid; i < 4096; i += 256) {
        int r = i >> 6, cc = i & 63;
        WT[(size_t)(bj + r) * DIM_ + bi + cc] = t[cc][r];
    }
}
__global__ void wt_kernel(const int* flag, const void* W, us* WT) {
    if (*flag) wt_body<us>((const us*)W, WT);
    else wt_body<float>((const float*)W, WT);
}

// ---------------- MFMA batched expert MLP layer (64m x 64n tiles) ----------------
template <typename T, int M, int K, int L1>
__device__ void mlp_body(const T* W, const T* bias, const T* pp, const T* pg,
                         const us* X, us* Y) {
    int e = blockIdx.z, mt = blockIdx.y, nt = blockIdx.x;
    int tid = threadIdx.x, w = tid >> 6, lane = tid & 63;
    int lm = lane & 15, quad = lane >> 4, kq = quad * 8;
    const int RS = L1 ? 1024 : K;
    const int KX = L1 ? 1024 : K;
    int s0 = nt * 64;
    const T* Ap = W + ((size_t)e * M + mt * 64 + w * 16 + lm) * K + kq;
    const us* Xp = X + ((size_t)(L1 ? 0 : e * NSETS) + s0 + lm) * RS + kq;
    f32x4 acc[4];
#pragma unroll
    for (int j = 0; j < 4; ++j) acc[j] = (f32x4){0.f, 0.f, 0.f, 0.f};

#pragma unroll 2
    for (int kc = 0; kc < KX; kc += 32) {
        bf16x8 a = loadA(Ap + kc);
#pragma unroll
        for (int j = 0; j < 4; ++j) {
            bf16x8 b = *(const bf16x8*)(Xp + kc + (size_t)j * 16 * RS);
            acc[j] = __builtin_amdgcn_mfma_f32_16x16x32_bf16(a, b, acc[j], 0, 0, 0);
        }
    }
    if (L1) {
        const T* P = (s0 < 128 ? pp : pg) + (size_t)e * DIM_ + kq;
#pragma unroll 2
        for (int kc = 0; kc < 512; kc += 32) {
            bf16x8 a = loadA(Ap + 1024 + kc);
            bf16x8 b = loadA(P + kc);
#pragma unroll
            for (int j = 0; j < 4; ++j)
                acc[j] = __builtin_amdgcn_mfma_f32_16x16x32_bf16(a, b, acc[j], 0, 0, 0);
        }
    }
    int m0 = mt * 64 + w * 16 + quad * 4;
    float bv[4];
#pragma unroll
    for (int r = 0; r < 4; ++r) bv[r] = ldT(bias + (size_t)e * M + m0 + r);
#pragma unroll
    for (int j = 0; j < 4; ++j) {
        int s = s0 + j * 16 + lm;
        us4 pk;
#pragma unroll
        for (int r = 0; r < 4; ++r) {
            float v = acc[j][r] + bv[r];
            v = v > 0.f ? v : 0.01f * v;
            pk[r] = f2b(v);
        }
        *(us4*)(Y + ((size_t)e * NSETS + s) * M + m0) = pk;
    }
}
template <int M, int K, int L1>
__global__ void mlp_kernel(const int* flag, const void* W, const void* bias,
                           const void* pp, const void* pg, const us* X, us* Y) {
    if (*flag)
        mlp_body<us, M, K, L1>((const us*)W, (const us*)bias, (const us*)pp, (const us*)pg, X, Y);
    else
        mlp_body<float, M, K, L1>((const float*)W, (const float*)bias, (const float*)pp, (const float*)pg, X, Y);
}

// ---------------- fold: CTXW[row][j] = sum_d CTX[row][d] * W[d][j]  (probe rows only) ----------------
__global__ void fold_kernel(const us* CTX, const us* WT, us* CTXW) {
    int nt = blockIdx.x, mtb = blockIdx.y;          // (8, 22)
    int e = mtb >> 1, sub = mtb & 1;
    int row0 = e * NSETS + sub * 64;
    int tid = threadIdx.x, w = tid >> 6, lane = tid & 63;
    int lm = lane & 15, quad = lane >> 4, kq = quad * 8;
    const us* Ap = CTX + ((size_t)row0 + w * 16 + lm) * DIM_ + kq;
    int n0 = nt * 64;
    const us* Bp = WT + (size_t)(n0 + lm) * DIM_ + kq;
    f32x4 acc[4];
#pragma unroll
    for (int j = 0; j < 4; ++j) acc[j] = (f32x4){0.f, 0.f, 0.f, 0.f};
#pragma unroll 2
    for (int kc = 0; kc < DIM_; kc += 32) {
        bf16x8 a = *(const bf16x8*)(Ap + kc);
#pragma unroll
        for (int j = 0; j < 4; ++j) {
            bf16x8 b = *(const bf16x8*)(Bp + kc + (size_t)j * 16 * DIM_);
            acc[j] = __builtin_amdgcn_mfma_f32_16x16x32_bf16(a, b, acc[j], 0, 0, 0);
        }
    }
    int mrow = row0 + w * 16 + quad * 4;
#pragma unroll
    for (int j = 0; j < 4; ++j)
#pragma unroll
        for (int r = 0; r < 4; ++r)
            CTXW[(size_t)(mrow + r) * DIM_ + n0 + j * 16 + lm] = f2b(acc[j][r]);
}

// ---------------- s0 = pb . ctx for every (e,s) row ----------------
template <typename T>
__device__ void s0a_body(const us* CTX, const T* pb, float* S0A) {
    int tid = threadIdx.x, w = tid >> 6, lane = tid & 63;
    int row = blockIdx.x * 4 + w;               // 528 blocks -> 2112 rows
    bf16x8 cv = *(const bf16x8*)(CTX + (size_t)row * DIM_ + lane * 8);
    float s = 0.f;
#pragma unroll
    for (int j = 0; j < 8; ++j) s += b2f((us)cv[j]) * ldT(pb + lane * 8 + j);
#pragma unroll
    for (int off = 32; off >= 1; off >>= 1) s += __shfl_xor(s, off, 64);
    if (lane == 0) S0A[row] = s;
}
__global__ void s0a_kernel(const int* flag, const us* CTX, const void* pb, float* S0A) {
    if (*flag) s0a_body<us>(CTX, (const us*)pb, S0A);
    else s0a_body<float>(CTX, (const float*)pb, S0A);
}

// ---------------- score: per-row dots + invn ----------------
template <typename T>
__device__ void score_body(const T* probes, const T* gallery, const int* plen,
                           const int* glen, float* wsf) {
    int bx = blockIdx.x, set = bx >> 2, c = bx & 3;
    bool probe = set < NPROBE;
    int L = probe ? LPR : LGA;
    const T* feat = probe ? probes + (size_t)set * L * DIM_
                          : gallery + (size_t)(set - NPROBE) * L * DIM_;
    int len = probe ? plen[set] : glen[set - NPROBE];
    int len_eff = min(max(len, 1), L);
    int r0 = c * (L / 4), r1 = min(r0 + L / 4, len_eff);
    if (r0 >= r1) return;
    int tid = threadIdx.x, w = tid >> 6, lane = tid & 63;
    const int* idx4 = (const int*)(wsf + F_IDX);
    const us* CTXW = (const us*)(wsf + F_CTXW);
    const us* CTXR = (const us*)(wsf + F_CTX);
    float cx[4][8], s0r[4];
#pragma unroll
    for (int k = 0; k < 4; ++k) {
        int row = idx4[set * 4 + k] * NSETS + set;
        const us* src = (probe ? CTXW : CTXR) + (size_t)row * DIM_ + lane * 8;
        bf16x8 v = *(const bf16x8*)src;
#pragma unroll
        for (int j = 0; j < 8; ++j) cx[k][j] = b2f((us)v[j]);
        s0r[k] = probe ? wsf[F_S0A + row] : 0.f;
    }
    float* wcoef = wsf + F_WCOEF;
    float* invn = wsf + F_INVN;
    for (int l = r0 + w; l < r1; l += 8) {
        float f[8];
        if constexpr (sizeof(T) == 2) {
            u32x4 raw = *(const u32x4*)(feat + (size_t)l * DIM_ + lane * 8);
#pragma unroll
            for (int q = 0; q < 4; ++q) {
                f[2*q]   = __uint_as_float(raw[q] << 16);
                f[2*q+1] = __uint_as_float(raw[q] & 0xFFFF0000u);
            }
        } else {
            const T* rp = feat + (size_t)l * DIM_ + lane * 8;
            f32x4 ra = *(const f32x4*)rp, rb = *(const f32x4*)(rp + 4);
#pragma unroll
            for (int j = 0; j < 4; ++j) { f[j] = ra[j]; f[4+j] = rb[j]; }
        }
        float sq = 0.f, d0 = 0.f, d1 = 0.f, d2 = 0.f, d3 = 0.f;
#pragma unroll
        for (int j = 0; j < 8; ++j) {
            float x = f[j];
            sq += x * x;
            d0 += x * cx[0][j]; d1 += x * cx[1][j];
            d2 += x * cx[2][j]; d3 += x * cx[3][j];
        }
#pragma unroll
        for (int off = 32; off >= 1; off >>= 1) {
            sq += __shfl_xor(sq, off, 64);
            d0 += __shfl_xor(d0, off, 64);
            d1 += __shfl_xor(d1, off, 64);
            d2 += __shfl_xor(d2, off, 64);
            d3 += __shfl_xor(d3, off, 64);
        }
        if (lane == 0) {
            invn[(size_t)set * 512 + l] = 1.0f / fmaxf(sqrtf(sq), 1e-12f);
            float* wc = wcoef + (size_t)set * 2048 + l * 4;
            wc[0] = d0 + s0r[0]; wc[1] = d1 + s0r[1];
            wc[2] = d2 + s0r[2]; wc[3] = d3 + s0r[3];
        }
    }
}
__global__ __launch_bounds__(512) void score_kernel(const int* flag, const void* probes,
        const void* gallery, const int* plen, const int* glen, float* wsf) {
    if (*flag) score_body<us>((const us*)probes, (const us*)gallery, plen, glen, wsf);
    else score_body<float>((const float*)probes, (const float*)gallery, plen, glen, wsf);
}

// ---------------- softmax over rows per (set, k), fold invn ----------------
__global__ void softmax_kernel(const int* plen, const int* glen, float* wsf) {
    int set = blockIdx.x, tid = threadIdx.x, k = tid >> 6, lane = tid & 63;
    bool probe = set < NPROBE;
    int L = probe ? LPR : LGA;
    int len = probe ? plen[set] : glen[set - NPROBE];
    int len_eff = min(max(len, 1), L);
    float* wcoef = wsf + F_WCOEF + (size_t)set * 2048;
    const float* invn = wsf + F_INVN + (size_t)set * 512;
    float cv[8];
    int n = 0;
    float m = -3e38f;
    for (int l = lane; l < len_eff; l += 64) {
        cv[n] = wcoef[l * 4 + k];
        m = fmaxf(m, cv[n]);
        ++n;
    }
#pragma unroll
    for (int off = 32; off >= 1; off >>= 1) m = fmaxf(m, __shfl_xor(m, off, 64));
    float se = 0.f;
    for (int i = 0; i < n; ++i) se += __expf(cv[i] - m);
#pragma unroll
    for (int off = 32; off >= 1; off >>= 1) se += __shfl_xor(se, off, 64);
    float invs = 1.0f / se;
    n = 0;
    for (int l = lane; l < len_eff; l += 64) {
        wcoef[l * 4 + k] = __expf(cv[n] - m) * invs * invn[l];
        ++n;
    }
}

// ---------------- accum: partial weighted sums per chunk ----------------
template <typename T>
__device__ void accum_body(const T* probes, const T* gallery, const int* plen,
                           const int* glen, float* wsf) {
    int bx = blockIdx.x, set = bx >> 2, c = bx & 3;
    bool probe = set < NPROBE;
    int L = probe ? LPR : LGA;
    const T* feat = probe ? probes + (size_t)set * L * DIM_
                          : gallery + (size_t)(set - NPROBE) * L * DIM_;
    int len = probe ? plen[set] : glen[set - NPROBE];
    int len_eff = min(max(len, 1), L);
    int r0 = c * (L / 4), r1 = min(r0 + L / 4, len_eff);
    int tid = threadIdx.x;
    __shared__ float cf[512];
    int nr = r1 - r0;
    const float* wcoef = wsf + F_WCOEF + (size_t)set * 2048 + r0 * 4;
    for (int p = tid; p < nr * 4; p += 512) cf[p] = wcoef[p];
    __syncthreads();
    float ac[4] = {0.f, 0.f, 0.f, 0.f};
#pragma unroll 2
    for (int l = r0; l < r1; ++l) {
        float x = ldT(feat + (size_t)l * DIM_ + tid);
        f32x4 cc = *(const f32x4*)&cf[(l - r0) * 4];
        ac[0] += x * cc[0]; ac[1] += x * cc[1];
        ac[2] += x * cc[2]; ac[3] += x * cc[3];
    }
    float* P = wsf + F_ACC + (size_t)bx * 2048;
#pragma unroll
    for (int k = 0; k < 4; ++k) P[k * 512 + tid] = ac[k];
}
__global__ __launch_bounds__(512) void accum_kernel(const int* flag, const void* probes,
        const void* gallery, const int* plen, const int* glen, float* wsf) {
    if (*flag) accum_body<us>((const us*)probes, (const us*)gallery, plen, glen, wsf);
    else accum_body<float>((const float*)probes, (const float*)gallery, plen, glen, wsf);
}

// ---------------- reduce 4 chunks -> output ----------------
template <typename T>
__device__ void reduce_body(const float* wsf, T* dout) {
    int set = blockIdx.x, d = threadIdx.x;
    const float* A = wsf + F_ACC + (size_t)set * 4 * 2048;
    size_t ob = (set < NPROBE) ? O_OUT1 + (size_t)set * 2048
                               : O_OUT3 + (size_t)(set - NPROBE) * 2048;
#pragma unroll
    for (int k = 0; k < 4; ++k) {
        float s = A[k * 512 + d] + A[2048 + k * 512 + d] + A[4096 + k * 512 + d] + A[6144 + k * 512 + d];
        stT(dout + ob + k * 512 + d, s);
    }
}
__global__ __launch_bounds__(512) void reduce_kernel(const int* flag, const float* wsf, void* dout) {
    if (*flag) reduce_body<us>(wsf, (us*)dout);
    else reduce_body<float>(wsf, (float*)dout);
}

}  // namespace

extern "C" void kernel_launch(void* const* d_in, const int* in_sizes, int n_in,
                              void* d_out, int out_size, void* d_ws, size_t ws_size,
                              hipStream_t stream) {
    if (ws_size < WS_BYTES) return;
    float* wsf = (float*)d_ws;
    int* flag = (int*)d_ws;
    us* SUMM = (us*)(wsf + F_SUMM);
    us* H1 = (us*)(wsf + F_H1);
    us* H2 = (us*)(wsf + F_H2);
    us* CTXb = (us*)(wsf + F_CTX);
    us* CTXW = (us*)(wsf + F_CTXW);
    us* WT = (us*)(wsf + F_WT);
    const int* plen = (const int*)d_in[2];
    const int* glen = (const int*)d_in[3];

    detect_kernel<<<1, 64, 0, stream>>>((const unsigned int*)d_in[8], flag);
    proxies_kernel<<<22, 64, 0, stream>>>(flag, d_in[4], d_in[5], d_in[6], d_in[7], wsf, d_out);
    wt_kernel<<<dim3(8, 8), 256, 0, stream>>>(flag, d_in[8], WT);
    stats_kernel<float><<<NSETS * 4, 1024, 0, stream>>>(flag, (const float*)d_in[0],
        (const float*)d_in[1], plen, glen, (const float*)d_in[6], wsf);
    stats_kernel<us><<<NSETS * 4, 1024, 0, stream>>>(flag, (const us*)d_in[0],
        (const us*)d_in[1], plen, glen, (const us*)d_in[6], wsf);
    statsfin_kernel<<<NSETS, 256, 0, stream>>>(plen, glen, wsf);
    mlp_kernel<1024, 1536, 1><<<dim3(3, 16, KALL), 256, 0, stream>>>(
        flag, d_in[10], d_in[11], d_in[4], d_in[5], SUMM, H1);
    mlp_kernel<1024, 1024, 0><<<dim3(3, 16, KALL), 256, 0, stream>>>(
        flag, d_in[12], d_in[13], d_in[4], d_in[5], H1, H2);
    mlp_kernel<512, 1024, 0><<<dim3(3, 8, KALL), 256, 0, stream>>>(
        flag, d_in[14], d_in[15], d_in[4], d_in[5], H2, CTXb);
    fold_kernel<<<dim3(8, 22), 256, 0, stream>>>(CTXb, WT, CTXW);
    s0a_kernel<<<528, 256, 0, stream>>>(flag, CTXb, d_in[9], wsf + F_S0A);
    score_kernel<<<NSETS * 4, 512, 0, stream>>>(flag, d_in[0], d_in[1], plen, glen, wsf);
    softmax_kernel<<<NSETS, 256, 0, stream>>>(plen, glen, wsf);
    accum_kernel<<<NSETS * 4, 512, 0, stream>>>(flag, d_in[0], d_in[1], plen, glen, wsf);
    reduce_kernel<<<NSETS, 512, 0, stream>>>(flag, wsf, d_out);
}

// Round 4
// 582.122 us; speedup vs baseline: 1.8955x; 1.0917x over previous
//
#include <hip/hip_runtime.h>
#include <hip/hip_bf16.h>

namespace {

using us = unsigned short;
typedef __attribute__((ext_vector_type(8))) short bf16x8;
typedef __attribute__((ext_vector_type(4))) float f32x4;
typedef __attribute__((ext_vector_type(4))) unsigned short us4;
typedef __attribute__((ext_vector_type(4))) unsigned int u32x4;

constexpr int DIM_ = 512, KALL = 11, DOM = 10, NPROBE = 128, NSETS = 192;
constexpr int LPR = 256, LGA = 512;

// output offsets (elements)
constexpr size_t O_OUT1 = 0;
constexpr size_t O_OUT2 = (size_t)NPROBE * 4 * DIM_;
constexpr size_t O_OUT3 = O_OUT2 + KALL * DOM;
constexpr size_t O_OUT4 = O_OUT3 + (size_t)64 * 4 * DIM_;

// workspace offsets (floats). flag int at [0].
constexpr size_t F_TP   = 64;       // 256 f
constexpr size_t F_IDX  = 320;      // 768 int
constexpr size_t F_S0A  = 1600;     // 2112 f
constexpr int    PSTR   = 1040;
constexpr size_t F_PART = 4096;                 // 768*1040
constexpr size_t F_WCOEF= 4096;                 // alias PART
constexpr size_t F_INVN = 397312;               // alias PART
constexpr size_t F_SUMM = 802816;               // bf16 [192][1024]
constexpr size_t F_H1   = 901120;               // bf16 [11][192][1024]
constexpr size_t F_CTXW = 901120;               // alias H1
constexpr size_t F_H2   = 1982464;
constexpr size_t F_ACC  = 1982464;              // alias H2+CTX
constexpr size_t F_CTX  = 3063808;              // bf16 [11][192][512]
constexpr size_t F_WT   = 3604480;              // bf16 [512][512]
constexpr size_t WS_FLOATS = 3735552;
constexpr size_t WS_BYTES = WS_FLOATS * 4;

__device__ __forceinline__ float b2f(us u) { return __uint_as_float(((unsigned)u) << 16); }
__device__ __forceinline__ us f2b(float x) {
    unsigned u = __float_as_uint(x);
    u += 0x7FFF + ((u >> 16) & 1);
    return (us)(u >> 16);
}
__device__ __forceinline__ float ldT(const float* p) { return *p; }
__device__ __forceinline__ float ldT(const us* p) { return b2f(*p); }
__device__ __forceinline__ void stT(float* p, float v) { *p = v; }
__device__ __forceinline__ void stT(us* p, float v) { *p = f2b(v); }

__device__ __forceinline__ bf16x8 loadA(const us* p) { return *(const bf16x8*)p; }
__device__ __forceinline__ bf16x8 loadA(const float* p) {
    f32x4 a = *(const f32x4*)p, b = *(const f32x4*)(p + 4);
    bf16x8 r;
#pragma unroll
    for (int j = 0; j < 4; ++j) { r[j] = (short)f2b(a[j]); r[4 + j] = (short)f2b(b[j]); }
    return r;
}

// async global->LDS, 16 B per lane
__device__ __forceinline__ void gload_lds16(const us* g, us* l) {
    __builtin_amdgcn_global_load_lds(
        (const __attribute__((address_space(1))) void*)g,
        (__attribute__((address_space(3))) void*)l, 16, 0, 0);
}

// ---------------- dtype detector ----------------
__global__ void detect_kernel(const unsigned int* probeW_bits, int* flag) {
    if (threadIdx.x == 0) *flag = (probeW_bits[0] == 0x3F800000u) ? 0 : 1;
}

// ---------------- proxies: out2/out4 + normalized tp ----------------
template <typename T>
__device__ void proxies_body(const T* pp, const T* pg, const T* tW, const T* tb,
                             float* wsf, T* dout) {
    int b = blockIdx.x;
    int fam = b / KALL, i = b % KALL;
    int lane = threadIdx.x;
    const T* src = fam ? pg : pp;
    float t[DOM];
#pragma unroll
    for (int r = 0; r < DOM; ++r) t[r] = 0.f;
    for (int d = lane; d < DIM_; d += 64) {
        float x = ldT(src + (size_t)i * DIM_ + d);
#pragma unroll
        for (int r = 0; r < DOM; ++r) t[r] += x * ldT(tW + (size_t)r * DIM_ + d);
    }
#pragma unroll
    for (int off = 32; off >= 1; off >>= 1)
#pragma unroll
        for (int r = 0; r < DOM; ++r) t[r] += __shfl_xor(t[r], off, 64);
#pragma unroll
    for (int r = 0; r < DOM; ++r) t[r] += ldT(tb + r);
    float nn = 0.f;
#pragma unroll
    for (int r = 0; r < DOM; ++r) nn += t[r] * t[r];
    float inv = 1.0f / fmaxf(sqrtf(nn), 1e-12f);
    if (lane < DOM) {
        size_t base = fam ? O_OUT4 : O_OUT2;
        stT(dout + base + i * DOM + lane, t[lane]);
        wsf[F_TP + fam * 128 + i * DOM + lane] = t[lane] * inv;
    }
}
__global__ void proxies_kernel(const int* flag, const void* pp, const void* pg,
                               const void* tW, const void* tb, float* wsf, void* dout) {
    if (*flag)
        proxies_body<us>((const us*)pp, (const us*)pg, (const us*)tW, (const us*)tb, wsf, (us*)dout);
    else
        proxies_body<float>((const float*)pp, (const float*)pg, (const float*)tW, (const float*)tb, wsf, (float*)dout);
}

// ---------------- per-set stats, chunked ----------------
// __launch_bounds__(512, 2): 2 waves/EU min -> VGPR cap 256 -> NO SPILLS
// (round-3 1024-thr version got capped at 64 VGPR and spilled ~40 MB to scratch)
template <typename T>
__global__ __launch_bounds__(512, 2) void stats_kernel(const int* flag, const T* probes,
        const T* gallery, const int* plen, const int* glen, const T* tW, float* wsf) {
    if (*flag != (int)(sizeof(T) == 2)) return;
    int bx = blockIdx.x, set = bx >> 2, c = bx & 3;
    bool probe = set < NPROBE;
    int L = probe ? LPR : LGA;
    const T* feat = probe ? probes + (size_t)set * L * DIM_
                          : gallery + (size_t)(set - NPROBE) * L * DIM_;
    int len = probe ? plen[set] : glen[set - NPROBE];
    int len_eff = min(max(len, 1), L);
    int r0 = c * (L / 4), r1 = min(r0 + L / 4, len_eff);

    __shared__ float tpl[KALL * DOM];
    __shared__ float psum[DIM_], psq[DIM_], gs[KALL];
    int tid = threadIdx.x;
    const float* tp = wsf + F_TP + (probe ? 0 : 128);
    if (tid < KALL * DOM) tpl[tid] = tp[tid];
    if (tid < KALL) gs[tid] = 0.f;
    psum[tid] = 0.f; psq[tid] = 0.f;
    __syncthreads();
    int w = tid >> 6, lane = tid & 63;
    float asum[8] = {0,0,0,0,0,0,0,0}, asq[8] = {0,0,0,0,0,0,0,0}, gacc = 0.f;

    if constexpr (sizeof(T) == 2) {
        unsigned wp[DOM][4];
#pragma unroll
        for (int r = 0; r < DOM; ++r)
#pragma unroll
            for (int q = 0; q < 4; ++q)
                wp[r][q] = *(const unsigned*)(tW + (size_t)r * DIM_ + lane * 8 + q * 2);
        for (int l = r0 + w; l < r1; l += 8) {
            u32x4 raw = *(const u32x4*)(feat + (size_t)l * DIM_ + lane * 8);
            float f[8];
#pragma unroll
            for (int q = 0; q < 4; ++q) {
                f[2*q]   = __uint_as_float(raw[q] << 16);
                f[2*q+1] = __uint_as_float(raw[q] & 0xFFFF0000u);
            }
            float t[DOM];
#pragma unroll
            for (int r = 0; r < DOM; ++r) {
                float s = 0.f;
#pragma unroll
                for (int q = 0; q < 4; ++q) {
                    unsigned u = wp[r][q];
                    s += f[2*q] * __uint_as_float(u << 16);
                    s += f[2*q+1] * __uint_as_float(u & 0xFFFF0000u);
                }
                t[r] = s;
            }
#pragma unroll
            for (int j = 0; j < 8; ++j) { asum[j] += f[j]; asq[j] += f[j] * f[j]; }
#pragma unroll
            for (int off = 32; off >= 1; off >>= 1)
#pragma unroll
                for (int r = 0; r < DOM; ++r) t[r] += __shfl_xor(t[r], off, 64);
            float nn = 0.f;
#pragma unroll
            for (int r = 0; r < DOM; ++r) nn += t[r] * t[r];
            float inv = 1.0f / fmaxf(sqrtf(nn), 1e-12f);
            if (lane < KALL) {
                float s = 0.f;
#pragma unroll
                for (int r = 0; r < DOM; ++r) s += t[r] * tpl[lane * DOM + r];
                gacc += s * inv;
            }
        }
    } else {
        float wreg[DOM][8];
#pragma unroll
        for (int r = 0; r < DOM; ++r)
#pragma unroll
            for (int j = 0; j < 8; ++j) wreg[r][j] = ldT(tW + (size_t)r * DIM_ + lane * 8 + j);
        for (int l = r0 + w; l < r1; l += 8) {
            const T* rp = feat + (size_t)l * DIM_ + lane * 8;
            f32x4 ra = *(const f32x4*)rp, rb = *(const f32x4*)(rp + 4);
            float f[8];
#pragma unroll
            for (int j = 0; j < 4; ++j) { f[j] = ra[j]; f[4+j] = rb[j]; }
            float t[DOM];
#pragma unroll
            for (int r = 0; r < DOM; ++r) {
                float s = 0.f;
#pragma unroll
                for (int j = 0; j < 8; ++j) s += f[j] * wreg[r][j];
                t[r] = s;
            }
#pragma unroll
            for (int j = 0; j < 8; ++j) { asum[j] += f[j]; asq[j] += f[j] * f[j]; }
#pragma unroll
            for (int off = 32; off >= 1; off >>= 1)
#pragma unroll
                for (int r = 0; r < DOM; ++r) t[r] += __shfl_xor(t[r], off, 64);
            float nn = 0.f;
#pragma unroll
            for (int r = 0; r < DOM; ++r) nn += t[r] * t[r];
            float inv = 1.0f / fmaxf(sqrtf(nn), 1e-12f);
            if (lane < KALL) {
                float s = 0.f;
#pragma unroll
                for (int r = 0; r < DOM; ++r) s += t[r] * tpl[lane * DOM + r];
                gacc += s * inv;
            }
        }
    }
    if (lane < KALL) atomicAdd(&gs[lane], gacc);
#pragma unroll
    for (int j = 0; j < 8; ++j) {
        atomicAdd(&psum[lane * 8 + j], asum[j]);
        atomicAdd(&psq[lane * 8 + j], asq[j]);
    }
    __syncthreads();
    float* P = wsf + F_PART + (size_t)bx * PSTR;
    P[tid] = psum[tid]; P[DIM_ + tid] = psq[tid];
    if (tid < KALL) P[1024 + tid] = gs[tid];
}

// ---------------- finalize stats: SUMM (bf16) + top4 ----------------
__global__ void statsfin_kernel(const int* plen, const int* glen, float* wsf) {
    int set = blockIdx.x, tid = threadIdx.x;
    bool probe = set < NPROBE;
    int len = probe ? plen[set] : glen[set - NPROBE];
    float lp = (float)max(len, 1);
    const float* P = wsf + F_PART + (size_t)set * 4 * PSTR;
    us* SUMM = (us*)(wsf + F_SUMM);
    for (int d = tid; d < DIM_; d += 256) {
        float s = P[d] + P[PSTR + d] + P[2 * PSTR + d] + P[3 * PSTR + d];
        float q = P[DIM_ + d] + P[PSTR + DIM_ + d] + P[2 * PSTR + DIM_ + d] + P[3 * PSTR + DIM_ + d];
        float m = s / lp;
        float v = q / lp - m * m;
        SUMM[(size_t)set * 1024 + d] = f2b(m);
        SUMM[(size_t)set * 1024 + DIM_ + d] = f2b(v);
    }
    if (tid == 0) {
        float g[KALL];
        for (int i = 0; i < KALL; ++i)
            g[i] = P[1024 + i] + P[PSTR + 1024 + i] + P[2 * PSTR + 1024 + i] + P[3 * PSTR + 1024 + i];
        int* idx4 = (int*)(wsf + F_IDX);
        for (int kk = 0; kk < 4; ++kk) {
            int bi = 0; float bv = g[0];
            for (int i = 1; i < KALL; ++i)
                if (g[i] > bv) { bv = g[i]; bi = i; }
            idx4[set * 4 + kk] = bi;
            g[bi] = -3e38f;
        }
    }
}

// ---------------- W transpose -> WT bf16 [j][d] ----------------
template <typename T>
__device__ void wt_body(const T* W, us* WT) {
    __shared__ us t[64][65];
    int bi = blockIdx.y * 64, bj = blockIdx.x * 64, tid = threadIdx.x;
    for (int i = tid; i < 4096; i += 256) {
        int r = i >> 6, cc = i & 63;
        t[r][cc] = (sizeof(T) == 2) ? ((const us*)W)[(size_t)(bi + r) * DIM_ + bj + cc]
                                    : f2b(ldT(W + (size_t)(bi + r) * DIM_ + bj + cc));
    }
    __syncthreads();
    for (int i = tid; i < 4096; i += 256) {
        int r = i >> 6, cc = i & 63;
        WT[(size_t)(bj + r) * DIM_ + bi + cc] = t[cc][r];
    }
}
__global__ void wt_kernel(const int* flag, const void* W, us* WT) {
    if (*flag) wt_body<us>((const us*)W, WT);
    else wt_body<float>((const float*)W, WT);
}

// ---------------- LDS-staged MFMA MLP (bf16 fast path) ----------------
// Block 256 thr = 4 waves, tile 64m x 64n, K-chunk 128 staged via global_load_lds.
// LDS layout XOR-swizzled: elem (r, c16-group) stored at col group c16 = csrc ^ (r&7).
template <int M, int KTOT, int L1>
__global__ __launch_bounds__(256) void mlp_staged(const int* flag, const us* W,
        const us* bias, const us* pp, const us* pg, const us* X, us* Y) {
    if (*flag != 1) return;
    constexpr int KC = 128;
    __shared__ us SM[16384];                 // A: [0,8192), B: [8192,16384)
    us* As = SM;
    us* Bs = SM + 8192;
    int e = blockIdx.z, mt = blockIdx.y, nt = blockIdx.x;
    int tid = threadIdx.x, w = tid >> 6, lane = tid & 63;
    int lm = lane & 15, quad = lane >> 4;
    const int RS = L1 ? 1024 : KTOT;
    int s0 = nt * 64;

    // staging geometry: inst i covers rows i*16 + (tid>>4), col group c16 = tid&15
    int srow = tid >> 4;                      // 0..15
    int csrc = (tid & 15) ^ (srow & 7);       // source col group (i-independent)
    int ldso = (tid & 15) * 0;                // (unused)
    us* lA = As + w * 512 + lane * 8;         // + i*2048
    us* lB = Bs + w * 512 + lane * 8;
    const us* Abase = W + ((size_t)e * M + mt * 64 + srow) * KTOT + csrc * 8;
    // B source row (for X-region chunks)
    const us* Xbase = X + ((size_t)(L1 ? 0 : e * NSETS) + s0 + srow) * RS + csrc * 8;
    const us* Pbase = (L1 ? ((nt < 2 ? pp : pg) + (size_t)e * DIM_ + csrc * 8) : nullptr);

    f32x4 acc[4];
#pragma unroll
    for (int j = 0; j < 4; ++j) acc[j] = (f32x4){0.f, 0.f, 0.f, 0.f};

    int ar = w * 16 + lm;                     // a-frag row
    int aswz = ar & 7;

    for (int k0 = 0; k0 < KTOT; k0 += KC) {
        __syncthreads();                      // prior chunk fully consumed
#pragma unroll
        for (int i = 0; i < 4; ++i)
            gload_lds16(Abase + (size_t)(i * 16) * KTOT + k0, lA + i * 2048);
        if (!L1 || k0 < 1024) {
#pragma unroll
            for (int i = 0; i < 4; ++i)
                gload_lds16(Xbase + (size_t)(i * 16) * RS + k0, lB + i * 2048);
        } else {
#pragma unroll
            for (int i = 0; i < 4; ++i)
                gload_lds16(Pbase + (k0 - 1024), lB + i * 2048);
        }
        __syncthreads();                      // staging visible (compiler drains vmcnt)
#pragma unroll
        for (int ks = 0; ks < 4; ++ks) {
            int cg = ks * 4 + quad;
            bf16x8 a = *(const bf16x8*)(As + ar * 128 + ((cg ^ aswz) * 8));
#pragma unroll
            for (int j = 0; j < 4; ++j) {
                int br = j * 16 + lm;
                bf16x8 b = *(const bf16x8*)(Bs + br * 128 + ((cg ^ (br & 7)) * 8));
                acc[j] = __builtin_amdgcn_mfma_f32_16x16x32_bf16(a, b, acc[j], 0, 0, 0);
            }
        }
    }
    int m0 = mt * 64 + w * 16 + quad * 4;
    float bv[4];
#pragma unroll
    for (int r = 0; r < 4; ++r) bv[r] = b2f(bias[(size_t)e * M + m0 + r]);
#pragma unroll
    for (int j = 0; j < 4; ++j) {
        int s = s0 + j * 16 + lm;
        us4 pk;
#pragma unroll
        for (int r = 0; r < 4; ++r) {
            float v = acc[j][r] + bv[r];
            v = v > 0.f ? v : 0.01f * v;
            pk[r] = f2b(v);
        }
        *(us4*)(Y + ((size_t)e * NSETS + s) * M + m0) = pk;
    }
}

// ---------------- fp32 fallback MLP (dead when inputs are bf16) ----------------
template <int M, int K, int L1>
__global__ void mlp_fb(const int* flag, const float* W, const float* bias,
                       const float* pp, const float* pg, const us* X, us* Y) {
    if (*flag != 0) return;
    int e = blockIdx.z, mt = blockIdx.y, nt = blockIdx.x;
    int tid = threadIdx.x, w = tid >> 6, lane = tid & 63;
    int lm = lane & 15, quad = lane >> 4, kq = quad * 8;
    const int RS = L1 ? 1024 : K;
    const int KX = L1 ? 1024 : K;
    int s0 = nt * 64;
    const float* Ap = W + ((size_t)e * M + mt * 64 + w * 16 + lm) * K + kq;
    const us* Xp = X + ((size_t)(L1 ? 0 : e * NSETS) + s0 + lm) * RS + kq;
    f32x4 acc[4];
#pragma unroll
    for (int j = 0; j < 4; ++j) acc[j] = (f32x4){0.f, 0.f, 0.f, 0.f};
#pragma unroll 2
    for (int kc = 0; kc < KX; kc += 32) {
        bf16x8 a = loadA(Ap + kc);
#pragma unroll
        for (int j = 0; j < 4; ++j) {
            bf16x8 b = *(const bf16x8*)(Xp + kc + (size_t)j * 16 * RS);
            acc[j] = __builtin_amdgcn_mfma_f32_16x16x32_bf16(a, b, acc[j], 0, 0, 0);
        }
    }
    if (L1) {
        const float* P = (s0 < 128 ? pp : pg) + (size_t)e * DIM_ + kq;
#pragma unroll 2
        for (int kc = 0; kc < 512; kc += 32) {
            bf16x8 a = loadA(Ap + 1024 + kc);
            bf16x8 b = loadA(P + kc);
#pragma unroll
            for (int j = 0; j < 4; ++j)
                acc[j] = __builtin_amdgcn_mfma_f32_16x16x32_bf16(a, b, acc[j], 0, 0, 0);
        }
    }
    int m0 = mt * 64 + w * 16 + quad * 4;
    float bv[4];
#pragma unroll
    for (int r = 0; r < 4; ++r) bv[r] = bias[(size_t)e * M + m0 + r];
#pragma unroll
    for (int j = 0; j < 4; ++j) {
        int s = s0 + j * 16 + lm;
        us4 pk;
#pragma unroll
        for (int r = 0; r < 4; ++r) {
            float v = acc[j][r] + bv[r];
            v = v > 0.f ? v : 0.01f * v;
            pk[r] = f2b(v);
        }
        *(us4*)(Y + ((size_t)e * NSETS + s) * M + m0) = pk;
    }
}

// ---------------- fold: CTXW = CTX @ W (probe side) ----------------
__global__ void fold_kernel(const us* CTX, const us* WT, us* CTXW) {
    int nt = blockIdx.x, mtb = blockIdx.y;          // (8, 22)
    int e = mtb >> 1, sub = mtb & 1;
    int row0 = e * NSETS + sub * 64;
    int tid = threadIdx.x, w = tid >> 6, lane = tid & 63;
    int lm = lane & 15, quad = lane >> 4, kq = quad * 8;
    const us* Ap = CTX + ((size_t)row0 + w * 16 + lm) * DIM_ + kq;
    int n0 = nt * 64;
    const us* Bp = WT + (size_t)(n0 + lm) * DIM_ + kq;
    f32x4 acc[4];
#pragma unroll
    for (int j = 0; j < 4; ++j) acc[j] = (f32x4){0.f, 0.f, 0.f, 0.f};
#pragma unroll 2
    for (int kc = 0; kc < DIM_; kc += 32) {
        bf16x8 a = *(const bf16x8*)(Ap + kc);
#pragma unroll
        for (int j = 0; j < 4; ++j) {
            bf16x8 b = *(const bf16x8*)(Bp + kc + (size_t)j * 16 * DIM_);
            acc[j] = __builtin_amdgcn_mfma_f32_16x16x32_bf16(a, b, acc[j], 0, 0, 0);
        }
    }
    int mrow = row0 + w * 16 + quad * 4;
#pragma unroll
    for (int j = 0; j < 4; ++j)
#pragma unroll
        for (int r = 0; r < 4; ++r)
            CTXW[(size_t)(mrow + r) * DIM_ + n0 + j * 16 + lm] = f2b(acc[j][r]);
}

// ---------------- s0 = pb . ctx ----------------
template <typename T>
__device__ void s0a_body(const us* CTX, const T* pb, float* S0A) {
    int tid = threadIdx.x, w = tid >> 6, lane = tid & 63;
    int row = blockIdx.x * 4 + w;
    bf16x8 cv = *(const bf16x8*)(CTX + (size_t)row * DIM_ + lane * 8);
    float s = 0.f;
#pragma unroll
    for (int j = 0; j < 8; ++j) s += b2f((us)cv[j]) * ldT(pb + lane * 8 + j);
#pragma unroll
    for (int off = 32; off >= 1; off >>= 1) s += __shfl_xor(s, off, 64);
    if (lane == 0) S0A[row] = s;
}
__global__ void s0a_kernel(const int* flag, const us* CTX, const void* pb, float* S0A) {
    if (*flag) s0a_body<us>(CTX, (const us*)pb, S0A);
    else s0a_body<float>(CTX, (const float*)pb, S0A);
}

// ---------------- score ----------------
template <typename T>
__device__ void score_body(const T* probes, const T* gallery, const int* plen,
                           const int* glen, float* wsf) {
    int bx = blockIdx.x, set = bx >> 2, c = bx & 3;
    bool probe = set < NPROBE;
    int L = probe ? LPR : LGA;
    const T* feat = probe ? probes + (size_t)set * L * DIM_
                          : gallery + (size_t)(set - NPROBE) * L * DIM_;
    int len = probe ? plen[set] : glen[set - NPROBE];
    int len_eff = min(max(len, 1), L);
    int r0 = c * (L / 4), r1 = min(r0 + L / 4, len_eff);
    if (r0 >= r1) return;
    int tid = threadIdx.x, w = tid >> 6, lane = tid & 63;
    const int* idx4 = (const int*)(wsf + F_IDX);
    const us* CTXW = (const us*)(wsf + F_CTXW);
    const us* CTXR = (const us*)(wsf + F_CTX);
    float cx[4][8], s0r[4];
#pragma unroll
    for (int k = 0; k < 4; ++k) {
        int row = idx4[set * 4 + k] * NSETS + set;
        const us* src = (probe ? CTXW : CTXR) + (size_t)row * DIM_ + lane * 8;
        bf16x8 v = *(const bf16x8*)src;
#pragma unroll
        for (int j = 0; j < 8; ++j) cx[k][j] = b2f((us)v[j]);
        s0r[k] = probe ? wsf[F_S0A + row] : 0.f;
    }
    float* wcoef = wsf + F_WCOEF;
    float* invn = wsf + F_INVN;
    for (int l = r0 + w; l < r1; l += 8) {
        float f[8];
        if constexpr (sizeof(T) == 2) {
            u32x4 raw = *(const u32x4*)(feat + (size_t)l * DIM_ + lane * 8);
#pragma unroll
            for (int q = 0; q < 4; ++q) {
                f[2*q]   = __uint_as_float(raw[q] << 16);
                f[2*q+1] = __uint_as_float(raw[q] & 0xFFFF0000u);
            }
        } else {
            const T* rp = feat + (size_t)l * DIM_ + lane * 8;
            f32x4 ra = *(const f32x4*)rp, rb = *(const f32x4*)(rp + 4);
#pragma unroll
            for (int j = 0; j < 4; ++j) { f[j] = ra[j]; f[4+j] = rb[j]; }
        }
        float sq = 0.f, d0 = 0.f, d1 = 0.f, d2 = 0.f, d3 = 0.f;
#pragma unroll
        for (int j = 0; j < 8; ++j) {
            float x = f[j];
            sq += x * x;
            d0 += x * cx[0][j]; d1 += x * cx[1][j];
            d2 += x * cx[2][j]; d3 += x * cx[3][j];
        }
#pragma unroll
        for (int off = 32; off >= 1; off >>= 1) {
            sq += __shfl_xor(sq, off, 64);
            d0 += __shfl_xor(d0, off, 64);
            d1 += __shfl_xor(d1, off, 64);
            d2 += __shfl_xor(d2, off, 64);
            d3 += __shfl_xor(d3, off, 64);
        }
        if (lane == 0) {
            invn[(size_t)set * 512 + l] = 1.0f / fmaxf(sqrtf(sq), 1e-12f);
            float* wc = wcoef + (size_t)set * 2048 + l * 4;
            wc[0] = d0 + s0r[0]; wc[1] = d1 + s0r[1];
            wc[2] = d2 + s0r[2]; wc[3] = d3 + s0r[3];
        }
    }
}
__global__ __launch_bounds__(512) void score_kernel(const int* flag, const void* probes,
        const void* gallery, const int* plen, const int* glen, float* wsf) {
    if (*flag) score_body<us>((const us*)probes, (const us*)gallery, plen, glen, wsf);
    else score_body<float>((const float*)probes, (const float*)gallery, plen, glen, wsf);
}

// ---------------- softmax ----------------
__global__ void softmax_kernel(const int* plen, const int* glen, float* wsf) {
    int set = blockIdx.x, tid = threadIdx.x, k = tid >> 6, lane = tid & 63;
    bool probe = set < NPROBE;
    int L = probe ? LPR : LGA;
    int len = probe ? plen[set] : glen[set - NPROBE];
    int len_eff = min(max(len, 1), L);
    float* wcoef = wsf + F_WCOEF + (size_t)set * 2048;
    const float* invn = wsf + F_INVN + (size_t)set * 512;
    float cv[8];
    int n = 0;
    float m = -3e38f;
    for (int l = lane; l < len_eff; l += 64) {
        cv[n] = wcoef[l * 4 + k];
        m = fmaxf(m, cv[n]);
        ++n;
    }
#pragma unroll
    for (int off = 32; off >= 1; off >>= 1) m = fmaxf(m, __shfl_xor(m, off, 64));
    float se = 0.f;
    for (int i = 0; i < n; ++i) se += __expf(cv[i] - m);
#pragma unroll
    for (int off = 32; off >= 1; off >>= 1) se += __shfl_xor(se, off, 64);
    float invs = 1.0f / se;
    n = 0;
    for (int l = lane; l < len_eff; l += 64) {
        wcoef[l * 4 + k] = __expf(cv[n] - m) * invs * invn[l];
        ++n;
    }
}

// ---------------- accum ----------------
template <typename T>
__device__ void accum_body(const T* probes, const T* gallery, const int* plen,
                           const int* glen, float* wsf) {
    int bx = blockIdx.x, set = bx >> 2, c = bx & 3;
    bool probe = set < NPROBE;
    int L = probe ? LPR : LGA;
    const T* feat = probe ? probes + (size_t)set * L * DIM_
                          : gallery + (size_t)(set - NPROBE) * L * DIM_;
    int len = probe ? plen[set] : glen[set - NPROBE];
    int len_eff = min(max(len, 1), L);
    int r0 = c * (L / 4), r1 = min(r0 + L / 4, len_eff);
    int tid = threadIdx.x;
    __shared__ float cf[512];
    int nr = r1 - r0;
    const float* wcoef = wsf + F_WCOEF + (size_t)set * 2048 + r0 * 4;
    for (int p = tid; p < nr * 4; p += 512) cf[p] = wcoef[p];
    __syncthreads();
    float ac[4] = {0.f, 0.f, 0.f, 0.f};
#pragma unroll 2
    for (int l = r0; l < r1; ++l) {
        float x = ldT(feat + (size_t)l * DIM_ + tid);
        f32x4 cc = *(const f32x4*)&cf[(l - r0) * 4];
        ac[0] += x * cc[0]; ac[1] += x * cc[1];
        ac[2] += x * cc[2]; ac[3] += x * cc[3];
    }
    float* P = wsf + F_ACC + (size_t)bx * 2048;
#pragma unroll
    for (int k = 0; k < 4; ++k) P[k * 512 + tid] = ac[k];
}
__global__ __launch_bounds__(512) void accum_kernel(const int* flag, const void* probes,
        const void* gallery, const int* plen, const int* glen, float* wsf) {
    if (*flag) accum_body<us>((const us*)probes, (const us*)gallery, plen, glen, wsf);
    else accum_body<float>((const float*)probes, (const float*)gallery, plen, glen, wsf);
}

// ---------------- reduce ----------------
template <typename T>
__device__ void reduce_body(const float* wsf, T* dout) {
    int set = blockIdx.x, d = threadIdx.x;
    const float* A = wsf + F_ACC + (size_t)set * 4 * 2048;
    size_t ob = (set < NPROBE) ? O_OUT1 + (size_t)set * 2048
                               : O_OUT3 + (size_t)(set - NPROBE) * 2048;
#pragma unroll
    for (int k = 0; k < 4; ++k) {
        float s = A[k * 512 + d] + A[2048 + k * 512 + d] + A[4096 + k * 512 + d] + A[6144 + k * 512 + d];
        stT(dout + ob + k * 512 + d, s);
    }
}
__global__ __launch_bounds__(512) void reduce_kernel(const int* flag, const float* wsf, void* dout) {
    if (*flag) reduce_body<us>(wsf, (us*)dout);
    else reduce_body<float>(wsf, (float*)dout);
}

}  // namespace

extern "C" void kernel_launch(void* const* d_in, const int* in_sizes, int n_in,
                              void* d_out, int out_size, void* d_ws, size_t ws_size,
                              hipStream_t stream) {
    if (ws_size < WS_BYTES) return;
    float* wsf = (float*)d_ws;
    int* flag = (int*)d_ws;
    us* SUMM = (us*)(wsf + F_SUMM);
    us* H1 = (us*)(wsf + F_H1);
    us* H2 = (us*)(wsf + F_H2);
    us* CTXb = (us*)(wsf + F_CTX);
    us* CTXW = (us*)(wsf + F_CTXW);
    us* WT = (us*)(wsf + F_WT);
    const int* plen = (const int*)d_in[2];
    const int* glen = (const int*)d_in[3];

    detect_kernel<<<1, 64, 0, stream>>>((const unsigned int*)d_in[8], flag);
    proxies_kernel<<<22, 64, 0, stream>>>(flag, d_in[4], d_in[5], d_in[6], d_in[7], wsf, d_out);
    wt_kernel<<<dim3(8, 8), 256, 0, stream>>>(flag, d_in[8], WT);
    stats_kernel<float><<<NSETS * 4, 512, 0, stream>>>(flag, (const float*)d_in[0],
        (const float*)d_in[1], plen, glen, (const float*)d_in[6], wsf);
    stats_kernel<us><<<NSETS * 4, 512, 0, stream>>>(flag, (const us*)d_in[0],
        (const us*)d_in[1], plen, glen, (const us*)d_in[6], wsf);
    statsfin_kernel<<<NSETS, 256, 0, stream>>>(plen, glen, wsf);

    mlp_staged<1024, 1536, 1><<<dim3(3, 16, KALL), 256, 0, stream>>>(
        flag, (const us*)d_in[10], (const us*)d_in[11], (const us*)d_in[4], (const us*)d_in[5], SUMM, H1);
    mlp_fb<1024, 1536, 1><<<dim3(3, 16, KALL), 256, 0, stream>>>(
        flag, (const float*)d_in[10], (const float*)d_in[11], (const float*)d_in[4], (const float*)d_in[5], SUMM, H1);
    mlp_staged<1024, 1024, 0><<<dim3(3, 16, KALL), 256, 0, stream>>>(
        flag, (const us*)d_in[12], (const us*)d_in[13], (const us*)d_in[4], (const us*)d_in[5], H1, H2);
    mlp_fb<1024, 1024, 0><<<dim3(3, 16, KALL), 256, 0, stream>>>(
        flag, (const float*)d_in[12], (const float*)d_in[13], (const float*)d_in[4], (const float*)d_in[5], H1, H2);
    mlp_staged<512, 1024, 0><<<dim3(3, 8, KALL), 256, 0, stream>>>(
        flag, (const us*)d_in[14], (const us*)d_in[15], (const us*)d_in[4], (const us*)d_in[5], H2, CTXb);
    mlp_fb<512, 1024, 0><<<dim3(3, 8, KALL), 256, 0, stream>>>(
        flag, (const float*)d_in[14], (const float*)d_in[15], (const float*)d_in[4], (const float*)d_in[5], H2, CTXb);

    fold_kernel<<<dim3(8, 22), 256, 0, stream>>>(CTXb, WT, CTXW);
    s0a_kernel<<<528, 256, 0, stream>>>(flag, CTXb, d_in[9], wsf + F_S0A);
    score_kernel<<<NSETS * 4, 512, 0, stream>>>(flag, d_in[0], d_in[1], plen, glen, wsf);
    softmax_kernel<<<NSETS, 256, 0, stream>>>(plen, glen, wsf);
    accum_kernel<<<NSETS * 4, 512, 0, stream>>>(flag, d_in[0], d_in[1], plen, glen, wsf);
    reduce_kernel<<<NSETS, 512, 0, stream>>>(flag, wsf, d_out);
}

// Round 5
// 543.858 us; speedup vs baseline: 2.0288x; 1.0704x over previous
//
#include <hip/hip_runtime.h>
#include <hip/hip_bf16.h>

namespace {

using us = unsigned short;
typedef __attribute__((ext_vector_type(8))) short bf16x8;
typedef __attribute__((ext_vector_type(4))) float f32x4;
typedef __attribute__((ext_vector_type(4))) unsigned short us4;
typedef __attribute__((ext_vector_type(4))) unsigned int u32x4;

constexpr int DIM_ = 512, KALL = 11, DOM = 10, NPROBE = 128, NSETS = 192;
constexpr int LPR = 256, LGA = 512;

// output offsets (elements)
constexpr size_t O_OUT1 = 0;
constexpr size_t O_OUT2 = (size_t)NPROBE * 4 * DIM_;
constexpr size_t O_OUT3 = O_OUT2 + KALL * DOM;
constexpr size_t O_OUT4 = O_OUT3 + (size_t)64 * 4 * DIM_;

// workspace layout (float units). flag int at [0].
// Lifetimes: PART(sums->statsfin) aliases H1(mlp1->mlp2) which later becomes
// CTXW(fold->score). ACC(accum->reduce) aliases H2+CTX (dead after score).
constexpr size_t F_TP   = 64;        // 256 f  normalized proxy transforms
constexpr size_t F_IDX  = 320;       // 768 i  top4 expert ids
constexpr size_t F_S0A  = 1600;      // 2112 f pb.ctx per (e,set)
constexpr size_t F_WQ   = 4096;      // [192][512][5] f32: scores k=0..3, invn at 4
constexpr size_t F_GP   = 495616;    // [1024][12] f32 gsim partials
constexpr size_t F_SUMM = 514048;    // bf16 [192][1024] mean|var
constexpr size_t F_H1   = 612352;    // bf16 [11][192][1024]
constexpr size_t F_PART = F_H1;      // [768][1024] f32 (psum|psq), dies before mlp1
constexpr size_t F_CTXW = F_H1;      // bf16 [11][192][512], after mlp2
constexpr size_t F_H2   = 1693696;   // bf16 [11][192][1024]
constexpr size_t F_ACC  = F_H2;      // [768][2048] f32, after score
constexpr size_t F_CTX  = 2775040;   // bf16 [11][192][512]
constexpr size_t F_WT   = 3315712;   // bf16 [512][512]
constexpr size_t WS_FLOATS = 3446784;
constexpr size_t WS_BYTES  = WS_FLOATS * 4;

__device__ __forceinline__ float b2f(us u) { return __uint_as_float(((unsigned)u) << 16); }
__device__ __forceinline__ us f2b(float x) {
    unsigned u = __float_as_uint(x);
    u += 0x7FFF + ((u >> 16) & 1);
    return (us)(u >> 16);
}
__device__ __forceinline__ float ldT(const float* p) { return *p; }
__device__ __forceinline__ float ldT(const us* p) { return b2f(*p); }
__device__ __forceinline__ void stT(float* p, float v) { *p = v; }
__device__ __forceinline__ void stT(us* p, float v) { *p = f2b(v); }

__device__ __forceinline__ bf16x8 loadA(const us* p) { return *(const bf16x8*)p; }
__device__ __forceinline__ bf16x8 loadA(const float* p) {
    f32x4 a = *(const f32x4*)p, b = *(const f32x4*)(p + 4);
    bf16x8 r;
#pragma unroll
    for (int j = 0; j < 4; ++j) { r[j] = (short)f2b(a[j]); r[4 + j] = (short)f2b(b[j]); }
    return r;
}

__device__ __forceinline__ void gload_lds16(const us* g, us* l) {
    __builtin_amdgcn_global_load_lds(
        (const __attribute__((address_space(1))) void*)g,
        (__attribute__((address_space(3))) void*)l, 16, 0, 0);
}

// decode 64-row-chunk grid (1024 blocks): probe 128x4, gallery 64x8
__device__ __forceinline__ void decode64(int bx, int& set, int& base, int& L) {
    if (bx < 512) { set = bx >> 2; base = (bx & 3) * 64; L = LPR; }
    else { set = NPROBE + ((bx - 512) >> 3); base = ((bx - 512) & 7) * 64; L = LGA; }
}

// ---------------- dtype detector ----------------
__global__ void detect_kernel(const unsigned int* probeW_bits, int* flag) {
    if (threadIdx.x == 0) *flag = (probeW_bits[0] == 0x3F800000u) ? 0 : 1;
}

// ---------------- proxies: out2/out4 + normalized tp ----------------
template <typename T>
__device__ void proxies_body(const T* pp, const T* pg, const T* tW, const T* tb,
                             float* wsf, T* dout) {
    int b = blockIdx.x;
    int fam = b / KALL, i = b % KALL;
    int lane = threadIdx.x;
    const T* src = fam ? pg : pp;
    float t[DOM];
#pragma unroll
    for (int r = 0; r < DOM; ++r) t[r] = 0.f;
    for (int d = lane; d < DIM_; d += 64) {
        float x = ldT(src + (size_t)i * DIM_ + d);
#pragma unroll
        for (int r = 0; r < DOM; ++r) t[r] += x * ldT(tW + (size_t)r * DIM_ + d);
    }
#pragma unroll
    for (int off = 32; off >= 1; off >>= 1)
#pragma unroll
        for (int r = 0; r < DOM; ++r) t[r] += __shfl_xor(t[r], off, 64);
#pragma unroll
    for (int r = 0; r < DOM; ++r) t[r] += ldT(tb + r);
    float nn = 0.f;
#pragma unroll
    for (int r = 0; r < DOM; ++r) nn += t[r] * t[r];
    float inv = 1.0f / fmaxf(sqrtf(nn), 1e-12f);
    if (lane < DOM) {
        size_t base = fam ? O_OUT4 : O_OUT2;
        stT(dout + base + i * DOM + lane, t[lane]);
        wsf[F_TP + fam * 128 + i * DOM + lane] = t[lane] * inv;
    }
}
__global__ void proxies_kernel(const int* flag, const void* pp, const void* pg,
                               const void* tW, const void* tb, float* wsf, void* dout) {
    if (*flag)
        proxies_body<us>((const us*)pp, (const us*)pg, (const us*)tW, (const us*)tb, wsf, (us*)dout);
    else
        proxies_body<float>((const float*)pp, (const float*)pg, (const float*)tW, (const float*)tb, wsf, (float*)dout);
}

// ---------------- pass A: per-dim sums/sumsq (registers) + per-row invn ----------------
template <typename T>
__device__ void sums_body(const T* probes, const T* gallery, const int* plen,
                          const int* glen, float* wsf) {
    int bx = blockIdx.x, set = bx >> 2, c = bx & 3;
    bool probe = set < NPROBE;
    int L = probe ? LPR : LGA;
    const T* feat = probe ? probes + (size_t)set * L * DIM_
                          : gallery + (size_t)(set - NPROBE) * L * DIM_;
    int len = probe ? plen[set] : glen[set - NPROBE];
    int len_eff = min(max(len, 1), L);
    int r0 = c * (L / 4), r1 = min(r0 + L / 4, len_eff);
    __shared__ float psum[DIM_], psq[DIM_];
    int tid = threadIdx.x, w = tid >> 6, lane = tid & 63;
    psum[tid] = 0.f; psum[tid + 256] = 0.f;
    psq[tid] = 0.f; psq[tid + 256] = 0.f;
    __syncthreads();
    float asum[8] = {0,0,0,0,0,0,0,0}, asq[8] = {0,0,0,0,0,0,0,0};
    float* wq = wsf + F_WQ + (size_t)set * 2560;
    for (int l = r0 + w * 2; l < r1; l += 8) {
        bool two = (l + 1 < r1);
        float f0[8], f1[8];
        if constexpr (sizeof(T) == 2) {
            u32x4 ra = *(const u32x4*)(feat + (size_t)l * DIM_ + lane * 8);
            u32x4 rb = two ? *(const u32x4*)(feat + (size_t)(l + 1) * DIM_ + lane * 8)
                           : (u32x4){0, 0, 0, 0};
#pragma unroll
            for (int q = 0; q < 4; ++q) {
                f0[2*q] = __uint_as_float(ra[q] << 16);
                f0[2*q+1] = __uint_as_float(ra[q] & 0xFFFF0000u);
                f1[2*q] = __uint_as_float(rb[q] << 16);
                f1[2*q+1] = __uint_as_float(rb[q] & 0xFFFF0000u);
            }
        } else {
            const T* rp = feat + (size_t)l * DIM_ + lane * 8;
            f32x4 a0 = *(const f32x4*)rp, a1 = *(const f32x4*)(rp + 4);
#pragma unroll
            for (int j = 0; j < 4; ++j) { f0[j] = a0[j]; f0[4+j] = a1[j]; }
            if (two) {
                const T* rq = feat + (size_t)(l + 1) * DIM_ + lane * 8;
                f32x4 b0 = *(const f32x4*)rq, b1 = *(const f32x4*)(rq + 4);
#pragma unroll
                for (int j = 0; j < 4; ++j) { f1[j] = b0[j]; f1[4+j] = b1[j]; }
            } else {
#pragma unroll
                for (int j = 0; j < 8; ++j) f1[j] = 0.f;
            }
        }
        float s0 = 0.f, s1 = 0.f;
#pragma unroll
        for (int j = 0; j < 8; ++j) {
            asum[j] += f0[j] + f1[j];
            asq[j] += f0[j] * f0[j] + f1[j] * f1[j];
            s0 += f0[j] * f0[j];
            s1 += f1[j] * f1[j];
        }
#pragma unroll
        for (int off = 32; off >= 1; off >>= 1) {
            s0 += __shfl_xor(s0, off, 64);
            s1 += __shfl_xor(s1, off, 64);
        }
        if (lane == 0) {
            wq[(size_t)l * 5 + 4] = 1.0f / fmaxf(sqrtf(s0), 1e-12f);
            if (two) wq[(size_t)(l + 1) * 5 + 4] = 1.0f / fmaxf(sqrtf(s1), 1e-12f);
        }
    }
#pragma unroll
    for (int j = 0; j < 8; ++j) {
        atomicAdd(&psum[lane * 8 + j], asum[j]);
        atomicAdd(&psq[lane * 8 + j], asq[j]);
    }
    __syncthreads();
    float* P = wsf + F_PART + (size_t)bx * 1024;
    P[tid] = psum[tid]; P[tid + 256] = psum[tid + 256];
    P[512 + tid] = psq[tid]; P[768 + tid] = psq[tid + 256];
}
__global__ __launch_bounds__(256) void sums_kernel(const int* flag, const void* probes,
        const void* gallery, const int* plen, const int* glen, float* wsf) {
    if (*flag) sums_body<us>((const us*)probes, (const us*)gallery, plen, glen, wsf);
    else sums_body<float>((const float*)probes, (const float*)gallery, plen, glen, wsf);
}

// ---------------- pass B: gsim via MFMA (feat @ tW^T), no per-row butterflies ----------------
template <typename T>
__device__ void sims_body(const T* probes, const T* gallery, const int* plen,
                          const int* glen, const T* tW, float* wsf) {
    int bx = blockIdx.x, set, base, L;
    decode64(bx, set, base, L);
    bool probe = set < NPROBE;
    int len = probe ? plen[set] : glen[set - NPROBE];
    int len_eff = min(max(len, 1), L);
    float* GP = wsf + F_GP + (size_t)bx * 12;
    int tid = threadIdx.x;
    if (base >= len_eff) { if (tid < KALL) GP[tid] = 0.f; return; }
    const T* feat = probe ? probes + (size_t)set * L * DIM_
                          : gallery + (size_t)(set - NPROBE) * L * DIM_;
    __shared__ __align__(16) float tile[4][320];   // [wave][16 rows][20 cols]
    __shared__ float tpl[KALL * DOM];
    __shared__ float gs[16];
    if (tid < KALL * DOM) tpl[tid] = wsf[F_TP + (probe ? 0 : 128) + tid];
    if (tid < 16) gs[tid] = 0.f;
    int w = tid >> 6, lane = tid & 63, lm = lane & 15, quad = lane >> 4;

    bf16x8 bq[16];
#pragma unroll
    for (int s = 0; s < 16; ++s) {
        if (lm < DOM) bq[s] = loadA(tW + (size_t)lm * DIM_ + s * 32 + quad * 8);
        else bq[s] = (bf16x8){0, 0, 0, 0, 0, 0, 0, 0};
    }
    int m0 = base + w * 16;
    const T* Ap = feat + (size_t)(m0 + lm) * DIM_ + quad * 8;
    f32x4 acc = (f32x4){0.f, 0.f, 0.f, 0.f};
#pragma unroll
    for (int s = 0; s < 16; ++s) {
        bf16x8 a = loadA(Ap + s * 32);
        acc = __builtin_amdgcn_mfma_f32_16x16x32_bf16(a, bq[s], acc, 0, 0, 0);
    }
#pragma unroll
    for (int r = 0; r < 4; ++r) tile[w][(quad * 4 + r) * 20 + lm] = acc[r];
    __syncthreads();

    float gacc[KALL];
#pragma unroll
    for (int k = 0; k < KALL; ++k) gacc[k] = 0.f;
    if (lane < 16) {
        int row = m0 + lane;
        if (row < len_eff) {
            const float* tr = &tile[w][lane * 20];
            f32x4 t0 = *(const f32x4*)tr, t1 = *(const f32x4*)(tr + 4);
            float tv[DOM] = {t0[0], t0[1], t0[2], t0[3], t1[0], t1[1], t1[2], t1[3], tr[8], tr[9]};
            float nn = 0.f;
#pragma unroll
            for (int r = 0; r < DOM; ++r) nn += tv[r] * tv[r];
            float inv = 1.0f / fmaxf(sqrtf(nn), 1e-12f);
#pragma unroll
            for (int k = 0; k < KALL; ++k) {
                float s = 0.f;
#pragma unroll
                for (int r = 0; r < DOM; ++r) s += tv[r] * tpl[k * DOM + r];
                gacc[k] = s * inv;
            }
        }
    }
#pragma unroll
    for (int off = 8; off >= 1; off >>= 1)
#pragma unroll
        for (int k = 0; k < KALL; ++k) gacc[k] += __shfl_xor(gacc[k], off, 64);
    if (lane == 0)
#pragma unroll
        for (int k = 0; k < KALL; ++k) atomicAdd(&gs[k], gacc[k]);
    __syncthreads();
    if (tid < KALL) GP[tid] = gs[tid];
}
__global__ __launch_bounds__(256, 3) void sims_kernel(const int* flag, const void* probes,
        const void* gallery, const int* plen, const int* glen, const void* tW, float* wsf) {
    if (*flag) sims_body<us>((const us*)probes, (const us*)gallery, plen, glen, (const us*)tW, wsf);
    else sims_body<float>((const float*)probes, (const float*)gallery, plen, glen, (const float*)tW, wsf);
}

// ---------------- finalize stats: SUMM (bf16) + top4 ----------------
__global__ void statsfin_kernel(const int* plen, const int* glen, float* wsf) {
    int set = blockIdx.x, tid = threadIdx.x;
    bool probe = set < NPROBE;
    int len = probe ? plen[set] : glen[set - NPROBE];
    float lp = (float)max(len, 1);
    const float* P = wsf + F_PART + (size_t)set * 4 * 1024;
    us* SUMM = (us*)(wsf + F_SUMM);
    for (int d = tid; d < DIM_; d += 256) {
        float s = P[d] + P[1024 + d] + P[2048 + d] + P[3072 + d];
        float q = P[512 + d] + P[1536 + d] + P[2560 + d] + P[3584 + d];
        float m = s / lp;
        float v = q / lp - m * m;
        SUMM[(size_t)set * 1024 + d] = f2b(m);
        SUMM[(size_t)set * 1024 + DIM_ + d] = f2b(v);
    }
    if (tid == 0) {
        int nch = probe ? 4 : 8;
        int gb = probe ? set * 4 : 512 + (set - NPROBE) * 8;
        float g[KALL];
        for (int i = 0; i < KALL; ++i) {
            float s = 0.f;
            for (int c = 0; c < nch; ++c) s += wsf[F_GP + (size_t)(gb + c) * 12 + i];
            g[i] = s;
        }
        int* idx4 = (int*)(wsf + F_IDX);
        for (int kk = 0; kk < 4; ++kk) {
            int bi = 0; float bv = g[0];
            for (int i = 1; i < KALL; ++i)
                if (g[i] > bv) { bv = g[i]; bi = i; }
            idx4[set * 4 + kk] = bi;
            g[bi] = -3e38f;
        }
    }
}

// ---------------- W transpose -> WT bf16 [j][d] ----------------
template <typename T>
__device__ void wt_body(const T* W, us* WT) {
    __shared__ us t[64][65];
    int bi = blockIdx.y * 64, bj = blockIdx.x * 64, tid = threadIdx.x;
    for (int i = tid; i < 4096; i += 256) {
        int r = i >> 6, cc = i & 63;
        t[r][cc] = (sizeof(T) == 2) ? ((const us*)W)[(size_t)(bi + r) * DIM_ + bj + cc]
                                    : f2b(ldT(W + (size_t)(bi + r) * DIM_ + bj + cc));
    }
    __syncthreads();
    for (int i = tid; i < 4096; i += 256) {
        int r = i >> 6, cc = i & 63;
        WT[(size_t)(bj + r) * DIM_ + bi + cc] = t[cc][r];
    }
}
__global__ void wt_kernel(const int* flag, const void* W, us* WT) {
    if (*flag) wt_body<us>((const us*)W, WT);
    else wt_body<float>((const float*)W, WT);
}

// ---------------- LDS-staged MFMA MLP (bf16 fast path) ----------------
template <int M, int KTOT, int L1>
__global__ __launch_bounds__(256) void mlp_staged(const int* flag, const us* W,
        const us* bias, const us* pp, const us* pg, const us* X, us* Y) {
    if (*flag != 1) return;
    constexpr int KC = 128;
    __shared__ us SM[16384];
    us* As = SM;
    us* Bs = SM + 8192;
    int e = blockIdx.z, mt = blockIdx.y, nt = blockIdx.x;
    int tid = threadIdx.x, w = tid >> 6, lane = tid & 63;
    int lm = lane & 15, quad = lane >> 4;
    const int RS = L1 ? 1024 : KTOT;
    int s0 = nt * 64;
    int srow = tid >> 4;
    int csrc = (tid & 15) ^ (srow & 7);
    us* lA = As + w * 512 + lane * 8;
    us* lB = Bs + w * 512 + lane * 8;
    const us* Abase = W + ((size_t)e * M + mt * 64 + srow) * KTOT + csrc * 8;
    const us* Xbase = X + ((size_t)(L1 ? 0 : e * NSETS) + s0 + srow) * RS + csrc * 8;
    const us* Pbase = (L1 ? ((nt < 2 ? pp : pg) + (size_t)e * DIM_ + csrc * 8) : nullptr);
    f32x4 acc[4];
#pragma unroll
    for (int j = 0; j < 4; ++j) acc[j] = (f32x4){0.f, 0.f, 0.f, 0.f};
    int ar = w * 16 + lm;
    int aswz = ar & 7;
    for (int k0 = 0; k0 < KTOT; k0 += KC) {
        __syncthreads();
#pragma unroll
        for (int i = 0; i < 4; ++i)
            gload_lds16(Abase + (size_t)(i * 16) * KTOT + k0, lA + i * 2048);
        if (!L1 || k0 < 1024) {
#pragma unroll
            for (int i = 0; i < 4; ++i)
                gload_lds16(Xbase + (size_t)(i * 16) * RS + k0, lB + i * 2048);
        } else {
#pragma unroll
            for (int i = 0; i < 4; ++i)
                gload_lds16(Pbase + (k0 - 1024), lB + i * 2048);
        }
        __syncthreads();
#pragma unroll
        for (int ks = 0; ks < 4; ++ks) {
            int cg = ks * 4 + quad;
            bf16x8 a = *(const bf16x8*)(As + ar * 128 + ((cg ^ aswz) * 8));
#pragma unroll
            for (int j = 0; j < 4; ++j) {
                int br = j * 16 + lm;
                bf16x8 b = *(const bf16x8*)(Bs + br * 128 + ((cg ^ (br & 7)) * 8));
                acc[j] = __builtin_amdgcn_mfma_f32_16x16x32_bf16(a, b, acc[j], 0, 0, 0);
            }
        }
    }
    int m0 = mt * 64 + w * 16 + quad * 4;
    float bv[4];
#pragma unroll
    for (int r = 0; r < 4; ++r) bv[r] = b2f(bias[(size_t)e * M + m0 + r]);
#pragma unroll
    for (int j = 0; j < 4; ++j) {
        int s = s0 + j * 16 + lm;
        us4 pk;
#pragma unroll
        for (int r = 0; r < 4; ++r) {
            float v = acc[j][r] + bv[r];
            v = v > 0.f ? v : 0.01f * v;
            pk[r] = f2b(v);
        }
        *(us4*)(Y + ((size_t)e * NSETS + s) * M + m0) = pk;
    }
}

// ---------------- fp32 fallback MLP ----------------
template <int M, int K, int L1>
__global__ void mlp_fb(const int* flag, const float* W, const float* bias,
                       const float* pp, const float* pg, const us* X, us* Y) {
    if (*flag != 0) return;
    int e = blockIdx.z, mt = blockIdx.y, nt = blockIdx.x;
    int tid = threadIdx.x, w = tid >> 6, lane = tid & 63;
    int lm = lane & 15, quad = lane >> 4, kq = quad * 8;
    const int RS = L1 ? 1024 : K;
    const int KX = L1 ? 1024 : K;
    int s0 = nt * 64;
    const float* Ap = W + ((size_t)e * M + mt * 64 + w * 16 + lm) * K + kq;
    const us* Xp = X + ((size_t)(L1 ? 0 : e * NSETS) + s0 + lm) * RS + kq;
    f32x4 acc[4];
#pragma unroll
    for (int j = 0; j < 4; ++j) acc[j] = (f32x4){0.f, 0.f, 0.f, 0.f};
#pragma unroll 2
    for (int kc = 0; kc < KX; kc += 32) {
        bf16x8 a = loadA(Ap + kc);
#pragma unroll
        for (int j = 0; j < 4; ++j) {
            bf16x8 b = *(const bf16x8*)(Xp + kc + (size_t)j * 16 * RS);
            acc[j] = __builtin_amdgcn_mfma_f32_16x16x32_bf16(a, b, acc[j], 0, 0, 0);
        }
    }
    if (L1) {
        const float* P = (s0 < 128 ? pp : pg) + (size_t)e * DIM_ + kq;
#pragma unroll 2
        for (int kc = 0; kc < 512; kc += 32) {
            bf16x8 a = loadA(Ap + 1024 + kc);
            bf16x8 b = loadA(P + kc);
#pragma unroll
            for (int j = 0; j < 4; ++j)
                acc[j] = __builtin_amdgcn_mfma_f32_16x16x32_bf16(a, b, acc[j], 0, 0, 0);
        }
    }
    int m0 = mt * 64 + w * 16 + quad * 4;
    float bv[4];
#pragma unroll
    for (int r = 0; r < 4; ++r) bv[r] = bias[(size_t)e * M + m0 + r];
#pragma unroll
    for (int j = 0; j < 4; ++j) {
        int s = s0 + j * 16 + lm;
        us4 pk;
#pragma unroll
        for (int r = 0; r < 4; ++r) {
            float v = acc[j][r] + bv[r];
            v = v > 0.f ? v : 0.01f * v;
            pk[r] = f2b(v);
        }
        *(us4*)(Y + ((size_t)e * NSETS + s) * M + m0) = pk;
    }
}

// ---------------- fold: CTXW = CTX @ W (probe rows) ----------------
__global__ void fold_kernel(const us* CTX, const us* WT, us* CTXW) {
    int nt = blockIdx.x, mtb = blockIdx.y;
    int e = mtb >> 1, sub = mtb & 1;
    int row0 = e * NSETS + sub * 64;
    int tid = threadIdx.x, w = tid >> 6, lane = tid & 63;
    int lm = lane & 15, quad = lane >> 4, kq = quad * 8;
    const us* Ap = CTX + ((size_t)row0 + w * 16 + lm) * DIM_ + kq;
    int n0 = nt * 64;
    const us* Bp = WT + (size_t)(n0 + lm) * DIM_ + kq;
    f32x4 acc[4];
#pragma unroll
    for (int j = 0; j < 4; ++j) acc[j] = (f32x4){0.f, 0.f, 0.f, 0.f};
#pragma unroll 2
    for (int kc = 0; kc < DIM_; kc += 32) {
        bf16x8 a = *(const bf16x8*)(Ap + kc);
#pragma unroll
        for (int j = 0; j < 4; ++j) {
            bf16x8 b = *(const bf16x8*)(Bp + kc + (size_t)j * 16 * DIM_);
            acc[j] = __builtin_amdgcn_mfma_f32_16x16x32_bf16(a, b, acc[j], 0, 0, 0);
        }
    }
    int mrow = row0 + w * 16 + quad * 4;
#pragma unroll
    for (int j = 0; j < 4; ++j)
#pragma unroll
        for (int r = 0; r < 4; ++r)
            CTXW[(size_t)(mrow + r) * DIM_ + n0 + j * 16 + lm] = f2b(acc[j][r]);
}

// ---------------- s0 = pb . ctx ----------------
template <typename T>
__device__ void s0a_body(const us* CTX, const T* pb, float* S0A) {
    int tid = threadIdx.x, w = tid >> 6, lane = tid & 63;
    int row = blockIdx.x * 4 + w;
    bf16x8 cv = *(const bf16x8*)(CTX + (size_t)row * DIM_ + lane * 8);
    float s = 0.f;
#pragma unroll
    for (int j = 0; j < 8; ++j) s += b2f((us)cv[j]) * ldT(pb + lane * 8 + j);
#pragma unroll
    for (int off = 32; off >= 1; off >>= 1) s += __shfl_xor(s, off, 64);
    if (lane == 0) S0A[row] = s;
}
__global__ void s0a_kernel(const int* flag, const us* CTX, const void* pb, float* S0A) {
    if (*flag) s0a_body<us>(CTX, (const us*)pb, S0A);
    else s0a_body<float>(CTX, (const float*)pb, S0A);
}

// ---------------- score: feat @ ctx^T via MFMA (zero cross-lane) ----------------
template <typename T>
__device__ void score_body(const T* probes, const T* gallery, const int* plen,
                           const int* glen, float* wsf) {
    int bx = blockIdx.x, set, base, L;
    decode64(bx, set, base, L);
    bool probe = set < NPROBE;
    int len = probe ? plen[set] : glen[set - NPROBE];
    int len_eff = min(max(len, 1), L);
    if (base >= len_eff) return;
    const T* feat = probe ? probes + (size_t)set * L * DIM_
                          : gallery + (size_t)(set - NPROBE) * L * DIM_;
    int tid = threadIdx.x, w = tid >> 6, lane = tid & 63;
    int lm = lane & 15, quad = lane >> 4;
    const int* idx4 = (const int*)(wsf + F_IDX);
    const us* CTXW = (const us*)(wsf + F_CTXW);
    const us* CTXR = (const us*)(wsf + F_CTX);
    bf16x8 bq[16];
    float s0v = 0.f;
    if (lm < 4) {
        int row = idx4[set * 4 + lm] * NSETS + set;
        const us* src = (probe ? CTXW : CTXR) + (size_t)row * DIM_ + quad * 8;
#pragma unroll
        for (int s = 0; s < 16; ++s) bq[s] = *(const bf16x8*)(src + s * 32);
        s0v = probe ? wsf[F_S0A + row] : 0.f;
    } else {
#pragma unroll
        for (int s = 0; s < 16; ++s) bq[s] = (bf16x8){0, 0, 0, 0, 0, 0, 0, 0};
    }
    int m0 = base + w * 16;
    const T* Ap = feat + (size_t)(m0 + lm) * DIM_ + quad * 8;
    f32x4 acc = (f32x4){0.f, 0.f, 0.f, 0.f};
#pragma unroll
    for (int s = 0; s < 16; ++s) {
        bf16x8 a = loadA(Ap + s * 32);
        acc = __builtin_amdgcn_mfma_f32_16x16x32_bf16(a, bq[s], acc, 0, 0, 0);
    }
    if (lm < 4) {
        float* wq = wsf + F_WQ + (size_t)set * 2560;
#pragma unroll
        for (int r = 0; r < 4; ++r) {
            int row = m0 + quad * 4 + r;
            wq[(size_t)row * 5 + lm] = acc[r] + s0v;
        }
    }
}
__global__ __launch_bounds__(256, 3) void score_kernel(const int* flag, const void* probes,
        const void* gallery, const int* plen, const int* glen, float* wsf) {
    if (*flag) score_body<us>((const us*)probes, (const us*)gallery, plen, glen, wsf);
    else score_body<float>((const float*)probes, (const float*)gallery, plen, glen, wsf);
}

// ---------------- softmax over rows per (set,k), fold invn ----------------
__global__ void softmax_kernel(const int* plen, const int* glen, float* wsf) {
    int set = blockIdx.x, tid = threadIdx.x, k = tid >> 6, lane = tid & 63;
    bool probe = set < NPROBE;
    int L = probe ? LPR : LGA;
    int len = probe ? plen[set] : glen[set - NPROBE];
    int len_eff = min(max(len, 1), L);
    float* wq = wsf + F_WQ + (size_t)set * 2560;
    float cv[8];
    int n = 0;
    float m = -3e38f;
    for (int l = lane; l < len_eff; l += 64) {
        cv[n] = wq[(size_t)l * 5 + k];
        m = fmaxf(m, cv[n]);
        ++n;
    }
#pragma unroll
    for (int off = 32; off >= 1; off >>= 1) m = fmaxf(m, __shfl_xor(m, off, 64));
    float se = 0.f;
    for (int i = 0; i < n; ++i) se += __expf(cv[i] - m);
#pragma unroll
    for (int off = 32; off >= 1; off >>= 1) se += __shfl_xor(se, off, 64);
    float invs = 1.0f / se;
    n = 0;
    for (int l = lane; l < len_eff; l += 64) {
        wq[(size_t)l * 5 + k] = __expf(cv[n] - m) * invs * wq[(size_t)l * 5 + 4];
        ++n;
    }
}

// ---------------- accum: weighted sums, u32 (bf16x2) coalesced, 2 row-groups ----------------
template <typename T>
__device__ void accum_body(const T* probes, const T* gallery, const int* plen,
                           const int* glen, float* wsf) {
    int bx = blockIdx.x, set = bx >> 2, c = bx & 3;
    bool probe = set < NPROBE;
    int L = probe ? LPR : LGA;
    const T* feat = probe ? probes + (size_t)set * L * DIM_
                          : gallery + (size_t)(set - NPROBE) * L * DIM_;
    int len = probe ? plen[set] : glen[set - NPROBE];
    int len_eff = min(max(len, 1), L);
    int r0 = c * (L / 4), r1 = min(r0 + L / 4, len_eff);
    int tid = threadIdx.x, g = tid >> 8, t = tid & 255;
    __shared__ float cf[512];
    __shared__ float pbuf[2048];
    int nr = r1 - r0;
    const float* wq = wsf + F_WQ + (size_t)set * 2560;
    for (int p = tid; p < nr * 4; p += 512)
        cf[p] = wq[(size_t)(r0 + (p >> 2)) * 5 + (p & 3)];
    __syncthreads();
    float ac[8] = {0.f, 0.f, 0.f, 0.f, 0.f, 0.f, 0.f, 0.f};
#pragma unroll 4
    for (int l = r0 + g; l < r1; l += 2) {
        float f0, f1;
        if constexpr (sizeof(T) == 2) {
            unsigned u = *(const unsigned*)((const us*)feat + (size_t)l * DIM_ + t * 2);
            f0 = __uint_as_float(u << 16);
            f1 = __uint_as_float(u & 0xFFFF0000u);
        } else {
            const T* rp = feat + (size_t)l * DIM_ + t * 2;
            f0 = rp[0]; f1 = rp[1];
        }
        f32x4 cc = *(const f32x4*)&cf[(l - r0) * 4];
#pragma unroll
        for (int k = 0; k < 4; ++k) {
            ac[k * 2] += f0 * cc[k];
            ac[k * 2 + 1] += f1 * cc[k];
        }
    }
    if (g == 1) {
#pragma unroll
        for (int i = 0; i < 8; ++i) pbuf[i * 256 + t] = ac[i];
    }
    __syncthreads();
    if (g == 0) {
        float* P = wsf + F_ACC + (size_t)bx * 2048;
#pragma unroll
        for (int k = 0; k < 4; ++k) {
            P[k * 512 + t * 2] = ac[k * 2] + pbuf[(k * 2) * 256 + t];
            P[k * 512 + t * 2 + 1] = ac[k * 2 + 1] + pbuf[(k * 2 + 1) * 256 + t];
        }
    }
}
__global__ __launch_bounds__(512) void accum_kernel(const int* flag, const void* probes,
        const void* gallery, const int* plen, const int* glen, float* wsf) {
    if (*flag) accum_body<us>((const us*)probes, (const us*)gallery, plen, glen, wsf);
    else accum_body<float>((const float*)probes, (const float*)gallery, plen, glen, wsf);
}

// ---------------- reduce ----------------
template <typename T>
__device__ void reduce_body(const float* wsf, T* dout) {
    int set = blockIdx.x, d = threadIdx.x;
    const float* A = wsf + F_ACC + (size_t)set * 4 * 2048;
    size_t ob = (set < NPROBE) ? O_OUT1 + (size_t)set * 2048
                               : O_OUT3 + (size_t)(set - NPROBE) * 2048;
#pragma unroll
    for (int k = 0; k < 4; ++k) {
        float s = A[k * 512 + d] + A[2048 + k * 512 + d] + A[4096 + k * 512 + d] + A[6144 + k * 512 + d];
        stT(dout + ob + k * 512 + d, s);
    }
}
__global__ __launch_bounds__(512) void reduce_kernel(const int* flag, const float* wsf, void* dout) {
    if (*flag) reduce_body<us>(wsf, (us*)dout);
    else reduce_body<float>(wsf, (float*)dout);
}

}  // namespace

extern "C" void kernel_launch(void* const* d_in, const int* in_sizes, int n_in,
                              void* d_out, int out_size, void* d_ws, size_t ws_size,
                              hipStream_t stream) {
    if (ws_size < WS_BYTES) return;
    float* wsf = (float*)d_ws;
    int* flag = (int*)d_ws;
    us* SUMM = (us*)(wsf + F_SUMM);
    us* H1 = (us*)(wsf + F_H1);
    us* H2 = (us*)(wsf + F_H2);
    us* CTXb = (us*)(wsf + F_CTX);
    us* CTXW = (us*)(wsf + F_CTXW);
    us* WT = (us*)(wsf + F_WT);
    const int* plen = (const int*)d_in[2];
    const int* glen = (const int*)d_in[3];

    detect_kernel<<<1, 64, 0, stream>>>((const unsigned int*)d_in[8], flag);
    proxies_kernel<<<22, 64, 0, stream>>>(flag, d_in[4], d_in[5], d_in[6], d_in[7], wsf, d_out);
    wt_kernel<<<dim3(8, 8), 256, 0, stream>>>(flag, d_in[8], WT);
    sums_kernel<<<NSETS * 4, 256, 0, stream>>>(flag, d_in[0], d_in[1], plen, glen, wsf);
    sims_kernel<<<1024, 256, 0, stream>>>(flag, d_in[0], d_in[1], plen, glen, d_in[6], wsf);
    statsfin_kernel<<<NSETS, 256, 0, stream>>>(plen, glen, wsf);

    mlp_staged<1024, 1536, 1><<<dim3(3, 16, KALL), 256, 0, stream>>>(
        flag, (const us*)d_in[10], (const us*)d_in[11], (const us*)d_in[4], (const us*)d_in[5], SUMM, H1);
    mlp_fb<1024, 1536, 1><<<dim3(3, 16, KALL), 256, 0, stream>>>(
        flag, (const float*)d_in[10], (const float*)d_in[11], (const float*)d_in[4], (const float*)d_in[5], SUMM, H1);
    mlp_staged<1024, 1024, 0><<<dim3(3, 16, KALL), 256, 0, stream>>>(
        flag, (const us*)d_in[12], (const us*)d_in[13], (const us*)d_in[4], (const us*)d_in[5], H1, H2);
    mlp_fb<1024, 1024, 0><<<dim3(3, 16, KALL), 256, 0, stream>>>(
        flag, (const float*)d_in[12], (const float*)d_in[13], (const float*)d_in[4], (const float*)d_in[5], H1, H2);
    mlp_staged<512, 1024, 0><<<dim3(3, 8, KALL), 256, 0, stream>>>(
        flag, (const us*)d_in[14], (const us*)d_in[15], (const us*)d_in[4], (const us*)d_in[5], H2, CTXb);
    mlp_fb<512, 1024, 0><<<dim3(3, 8, KALL), 256, 0, stream>>>(
        flag, (const float*)d_in[14], (const float*)d_in[15], (const float*)d_in[4], (const float*)d_in[5], H2, CTXb);

    fold_kernel<<<dim3(8, 22), 256, 0, stream>>>(CTXb, WT, CTXW);
    s0a_kernel<<<528, 256, 0, stream>>>(flag, CTXb, d_in[9], wsf + F_S0A);
    score_kernel<<<1024, 256, 0, stream>>>(flag, d_in[0], d_in[1], plen, glen, wsf);
    softmax_kernel<<<NSETS, 256, 0, stream>>>(plen, glen, wsf);
    accum_kernel<<<NSETS * 4, 512, 0, stream>>>(flag, d_in[0], d_in[1], plen, glen, wsf);
    reduce_kernel<<<NSETS, 512, 0, stream>>>(flag, wsf, d_out);
}

// Round 6
// 425.595 us; speedup vs baseline: 2.5926x; 1.2779x over previous
//
#include <hip/hip_runtime.h>
#include <hip/hip_bf16.h>

namespace {

using us = unsigned short;
typedef __attribute__((ext_vector_type(8))) short bf16x8;
typedef __attribute__((ext_vector_type(4))) float f32x4;
typedef __attribute__((ext_vector_type(4))) unsigned short us4;
typedef __attribute__((ext_vector_type(4))) unsigned int u32x4;

constexpr int DIM_ = 512, KALL = 11, DOM = 10, NPROBE = 128, NSETS = 192;
constexpr int LPR = 256, LGA = 512;

// output offsets (elements)
constexpr size_t O_OUT1 = 0;
constexpr size_t O_OUT2 = (size_t)NPROBE * 4 * DIM_;
constexpr size_t O_OUT3 = O_OUT2 + KALL * DOM;
constexpr size_t O_OUT4 = O_OUT3 + (size_t)64 * 4 * DIM_;

// workspace layout (float units). flag int at [0].
constexpr size_t F_TP   = 64;        // 256 f  normalized proxy transforms
constexpr size_t F_IDX  = 320;       // 768 i  top4 expert ids
constexpr size_t F_S0A  = 1600;      // 2112 f pb.ctx per (e,set)
constexpr size_t F_WQ   = 4096;      // [192][512][5] f32: scores k=0..3, invn at 4
constexpr size_t F_GP   = 495616;    // [1024][12] f32 gsim partials
constexpr size_t F_SUMM = 514048;    // bf16 [192][1024] mean|var
constexpr size_t F_H1   = 612352;    // bf16 [11][192][1024]
constexpr size_t F_PART = F_H1;      // [768][1024] f32 (psum|psq), dies before mlp1
constexpr size_t F_CTXW = F_H1;      // bf16 [11][192][512], after mlp2
constexpr size_t F_H2   = 1693696;   // bf16 [11][192][1024]
constexpr size_t F_ACC  = F_H2;      // [768][2048] f32, after score
constexpr size_t F_CTX  = 2775040;   // bf16 [11][192][512]
constexpr size_t F_WT   = 3315712;   // bf16 [512][512]
constexpr size_t WS_FLOATS = 3446784;
constexpr size_t WS_BYTES  = WS_FLOATS * 4;

__device__ __forceinline__ float b2f(us u) { return __uint_as_float(((unsigned)u) << 16); }
__device__ __forceinline__ us f2b(float x) {
    unsigned u = __float_as_uint(x);
    u += 0x7FFF + ((u >> 16) & 1);
    return (us)(u >> 16);
}
__device__ __forceinline__ float ldT(const float* p) { return *p; }
__device__ __forceinline__ float ldT(const us* p) { return b2f(*p); }
__device__ __forceinline__ void stT(float* p, float v) { *p = v; }
__device__ __forceinline__ void stT(us* p, float v) { *p = f2b(v); }

__device__ __forceinline__ bf16x8 loadA(const us* p) { return *(const bf16x8*)p; }
__device__ __forceinline__ bf16x8 loadA(const float* p) {
    f32x4 a = *(const f32x4*)p, b = *(const f32x4*)(p + 4);
    bf16x8 r;
#pragma unroll
    for (int j = 0; j < 4; ++j) { r[j] = (short)f2b(a[j]); r[4 + j] = (short)f2b(b[j]); }
    return r;
}

__device__ __forceinline__ void gload_lds16(const us* g, us* l) {
    __builtin_amdgcn_global_load_lds(
        (const __attribute__((address_space(1))) void*)g,
        (__attribute__((address_space(3))) void*)l, 16, 0, 0);
}

// decode 64-row-chunk grid (1024 blocks): probe 128x4, gallery 64x8
__device__ __forceinline__ void decode64(int bx, int& set, int& base, int& L) {
    if (bx < 512) { set = bx >> 2; base = (bx & 3) * 64; L = LPR; }
    else { set = NPROBE + ((bx - 512) >> 3); base = ((bx - 512) & 7) * 64; L = LGA; }
}

// ---------------- dtype detector ----------------
__global__ void detect_kernel(const unsigned int* probeW_bits, int* flag) {
    if (threadIdx.x == 0) *flag = (probeW_bits[0] == 0x3F800000u) ? 0 : 1;
}

// ---------------- proxies: out2/out4 + normalized tp ----------------
template <typename T>
__device__ void proxies_body(const T* pp, const T* pg, const T* tW, const T* tb,
                             float* wsf, T* dout) {
    int b = blockIdx.x;
    int fam = b / KALL, i = b % KALL;
    int lane = threadIdx.x;
    const T* src = fam ? pg : pp;
    float t[DOM];
#pragma unroll
    for (int r = 0; r < DOM; ++r) t[r] = 0.f;
    for (int d = lane; d < DIM_; d += 64) {
        float x = ldT(src + (size_t)i * DIM_ + d);
#pragma unroll
        for (int r = 0; r < DOM; ++r) t[r] += x * ldT(tW + (size_t)r * DIM_ + d);
    }
#pragma unroll
    for (int off = 32; off >= 1; off >>= 1)
#pragma unroll
        for (int r = 0; r < DOM; ++r) t[r] += __shfl_xor(t[r], off, 64);
#pragma unroll
    for (int r = 0; r < DOM; ++r) t[r] += ldT(tb + r);
    float nn = 0.f;
#pragma unroll
    for (int r = 0; r < DOM; ++r) nn += t[r] * t[r];
    float inv = 1.0f / fmaxf(sqrtf(nn), 1e-12f);
    if (lane < DOM) {
        size_t base = fam ? O_OUT4 : O_OUT2;
        stT(dout + base + i * DOM + lane, t[lane]);
        wsf[F_TP + fam * 128 + i * DOM + lane] = t[lane] * inv;
    }
}
__global__ void proxies_kernel(const int* flag, const void* pp, const void* pg,
                               const void* tW, const void* tb, float* wsf, void* dout) {
    if (*flag)
        proxies_body<us>((const us*)pp, (const us*)pg, (const us*)tW, (const us*)tb, wsf, (us*)dout);
    else
        proxies_body<float>((const float*)pp, (const float*)pg, (const float*)tW, (const float*)tb, wsf, (float*)dout);
}

// ---------------- pass A: per-dim sums/sumsq + per-row invn ----------------
template <typename T>
__device__ void sums_body(const T* probes, const T* gallery, const int* plen,
                          const int* glen, float* wsf) {
    int bx = blockIdx.x, set = bx >> 2, c = bx & 3;
    bool probe = set < NPROBE;
    int L = probe ? LPR : LGA;
    const T* feat = probe ? probes + (size_t)set * L * DIM_
                          : gallery + (size_t)(set - NPROBE) * L * DIM_;
    int len = probe ? plen[set] : glen[set - NPROBE];
    int len_eff = min(max(len, 1), L);
    int r0 = c * (L / 4), r1 = min(r0 + L / 4, len_eff);
    __shared__ float psum[DIM_], psq[DIM_];
    int tid = threadIdx.x, w = tid >> 6, lane = tid & 63;
    psum[tid] = 0.f; psum[tid + 256] = 0.f;
    psq[tid] = 0.f; psq[tid + 256] = 0.f;
    __syncthreads();
    float asum[8] = {0,0,0,0,0,0,0,0}, asq[8] = {0,0,0,0,0,0,0,0};
    float* wq = wsf + F_WQ + (size_t)set * 2560;
    for (int l = r0 + w * 2; l < r1; l += 8) {
        bool two = (l + 1 < r1);
        float f0[8], f1[8];
        if constexpr (sizeof(T) == 2) {
            u32x4 ra = *(const u32x4*)(feat + (size_t)l * DIM_ + lane * 8);
            u32x4 rb = two ? *(const u32x4*)(feat + (size_t)(l + 1) * DIM_ + lane * 8)
                           : (u32x4){0, 0, 0, 0};
#pragma unroll
            for (int q = 0; q < 4; ++q) {
                f0[2*q] = __uint_as_float(ra[q] << 16);
                f0[2*q+1] = __uint_as_float(ra[q] & 0xFFFF0000u);
                f1[2*q] = __uint_as_float(rb[q] << 16);
                f1[2*q+1] = __uint_as_float(rb[q] & 0xFFFF0000u);
            }
        } else {
            const T* rp = feat + (size_t)l * DIM_ + lane * 8;
            f32x4 a0 = *(const f32x4*)rp, a1 = *(const f32x4*)(rp + 4);
#pragma unroll
            for (int j = 0; j < 4; ++j) { f0[j] = a0[j]; f0[4+j] = a1[j]; }
            if (two) {
                const T* rq = feat + (size_t)(l + 1) * DIM_ + lane * 8;
                f32x4 b0 = *(const f32x4*)rq, b1 = *(const f32x4*)(rq + 4);
#pragma unroll
                for (int j = 0; j < 4; ++j) { f1[j] = b0[j]; f1[4+j] = b1[j]; }
            } else {
#pragma unroll
                for (int j = 0; j < 8; ++j) f1[j] = 0.f;
            }
        }
        float s0 = 0.f, s1 = 0.f;
#pragma unroll
        for (int j = 0; j < 8; ++j) {
            asum[j] += f0[j] + f1[j];
            asq[j] += f0[j] * f0[j] + f1[j] * f1[j];
            s0 += f0[j] * f0[j];
            s1 += f1[j] * f1[j];
        }
#pragma unroll
        for (int off = 32; off >= 1; off >>= 1) {
            s0 += __shfl_xor(s0, off, 64);
            s1 += __shfl_xor(s1, off, 64);
        }
        if (lane == 0) {
            wq[(size_t)l * 5 + 4] = 1.0f / fmaxf(sqrtf(s0), 1e-12f);
            if (two) wq[(size_t)(l + 1) * 5 + 4] = 1.0f / fmaxf(sqrtf(s1), 1e-12f);
        }
    }
#pragma unroll
    for (int j = 0; j < 8; ++j) {
        atomicAdd(&psum[lane * 8 + j], asum[j]);
        atomicAdd(&psq[lane * 8 + j], asq[j]);
    }
    __syncthreads();
    float* P = wsf + F_PART + (size_t)bx * 1024;
    P[tid] = psum[tid]; P[tid + 256] = psum[tid + 256];
    P[512 + tid] = psq[tid]; P[768 + tid] = psq[tid + 256];
}
__global__ __launch_bounds__(256) void sums_kernel(const int* flag, const void* probes,
        const void* gallery, const int* plen, const int* glen, float* wsf) {
    if (*flag) sums_body<us>((const us*)probes, (const us*)gallery, plen, glen, wsf);
    else sums_body<float>((const float*)probes, (const float*)gallery, plen, glen, wsf);
}

// ---------------- pass B: gsim via MFMA (feat @ tW^T) ----------------
template <typename T>
__device__ void sims_body(const T* probes, const T* gallery, const int* plen,
                          const int* glen, const T* tW, float* wsf) {
    int bx = blockIdx.x, set, base, L;
    decode64(bx, set, base, L);
    bool probe = set < NPROBE;
    int len = probe ? plen[set] : glen[set - NPROBE];
    int len_eff = min(max(len, 1), L);
    float* GP = wsf + F_GP + (size_t)bx * 12;
    int tid = threadIdx.x;
    if (base >= len_eff) { if (tid < KALL) GP[tid] = 0.f; return; }
    const T* feat = probe ? probes + (size_t)set * L * DIM_
                          : gallery + (size_t)(set - NPROBE) * L * DIM_;
    __shared__ __align__(16) float tile[4][320];   // [wave][16 rows][20 cols]
    __shared__ float tpl[KALL * DOM];
    __shared__ float gs[16];
    if (tid < KALL * DOM) tpl[tid] = wsf[F_TP + (probe ? 0 : 128) + tid];
    if (tid < 16) gs[tid] = 0.f;
    int w = tid >> 6, lane = tid & 63, lm = lane & 15, quad = lane >> 4;

    bf16x8 bq[16];
#pragma unroll
    for (int s = 0; s < 16; ++s) {
        if (lm < DOM) bq[s] = loadA(tW + (size_t)lm * DIM_ + s * 32 + quad * 8);
        else bq[s] = (bf16x8){0, 0, 0, 0, 0, 0, 0, 0};
    }
    int m0 = base + w * 16;
    const T* Ap = feat + (size_t)(m0 + lm) * DIM_ + quad * 8;
    f32x4 acc = (f32x4){0.f, 0.f, 0.f, 0.f};
#pragma unroll
    for (int s = 0; s < 16; ++s) {
        bf16x8 a = loadA(Ap + s * 32);
        acc = __builtin_amdgcn_mfma_f32_16x16x32_bf16(a, bq[s], acc, 0, 0, 0);
    }
#pragma unroll
    for (int r = 0; r < 4; ++r) tile[w][(quad * 4 + r) * 20 + lm] = acc[r];
    __syncthreads();

    float gacc[KALL];
#pragma unroll
    for (int k = 0; k < KALL; ++k) gacc[k] = 0.f;
    if (lane < 16) {
        int row = m0 + lane;
        if (row < len_eff) {
            const float* tr = &tile[w][lane * 20];
            f32x4 t0 = *(const f32x4*)tr, t1 = *(const f32x4*)(tr + 4);
            float tv[DOM] = {t0[0], t0[1], t0[2], t0[3], t1[0], t1[1], t1[2], t1[3], tr[8], tr[9]};
            float nn = 0.f;
#pragma unroll
            for (int r = 0; r < DOM; ++r) nn += tv[r] * tv[r];
            float inv = 1.0f / fmaxf(sqrtf(nn), 1e-12f);
#pragma unroll
            for (int k = 0; k < KALL; ++k) {
                float s = 0.f;
#pragma unroll
                for (int r = 0; r < DOM; ++r) s += tv[r] * tpl[k * DOM + r];
                gacc[k] = s * inv;
            }
        }
    }
#pragma unroll
    for (int off = 8; off >= 1; off >>= 1)
#pragma unroll
        for (int k = 0; k < KALL; ++k) gacc[k] += __shfl_xor(gacc[k], off, 64);
    if (lane == 0)
#pragma unroll
        for (int k = 0; k < KALL; ++k) atomicAdd(&gs[k], gacc[k]);
    __syncthreads();
    if (tid < KALL) GP[tid] = gs[tid];
}
__global__ __launch_bounds__(256, 3) void sims_kernel(const int* flag, const void* probes,
        const void* gallery, const int* plen, const int* glen, const void* tW, float* wsf) {
    if (*flag) sims_body<us>((const us*)probes, (const us*)gallery, plen, glen, (const us*)tW, wsf);
    else sims_body<float>((const float*)probes, (const float*)gallery, plen, glen, (const float*)tW, wsf);
}

// ---------------- finalize stats: SUMM (bf16) + top4 ----------------
__global__ void statsfin_kernel(const int* plen, const int* glen, float* wsf) {
    int set = blockIdx.x, tid = threadIdx.x;
    bool probe = set < NPROBE;
    int len = probe ? plen[set] : glen[set - NPROBE];
    float lp = (float)max(len, 1);
    const float* P = wsf + F_PART + (size_t)set * 4 * 1024;
    us* SUMM = (us*)(wsf + F_SUMM);
    for (int d = tid; d < DIM_; d += 256) {
        float s = P[d] + P[1024 + d] + P[2048 + d] + P[3072 + d];
        float q = P[512 + d] + P[1536 + d] + P[2560 + d] + P[3584 + d];
        float m = s / lp;
        float v = q / lp - m * m;
        SUMM[(size_t)set * 1024 + d] = f2b(m);
        SUMM[(size_t)set * 1024 + DIM_ + d] = f2b(v);
    }
    if (tid == 0) {
        int nch = probe ? 4 : 8;
        int gb = probe ? set * 4 : 512 + (set - NPROBE) * 8;
        float g[KALL];
        for (int i = 0; i < KALL; ++i) {
            float s = 0.f;
            for (int c = 0; c < nch; ++c) s += wsf[F_GP + (size_t)(gb + c) * 12 + i];
            g[i] = s;
        }
        int* idx4 = (int*)(wsf + F_IDX);
        for (int kk = 0; kk < 4; ++kk) {
            int bi = 0; float bv = g[0];
            for (int i = 1; i < KALL; ++i)
                if (g[i] > bv) { bv = g[i]; bi = i; }
            idx4[set * 4 + kk] = bi;
            g[bi] = -3e38f;
        }
    }
}

// ---------------- W transpose -> WT bf16 [j][d] ----------------
template <typename T>
__device__ void wt_body(const T* W, us* WT) {
    __shared__ us t[64][65];
    int bi = blockIdx.y * 64, bj = blockIdx.x * 64, tid = threadIdx.x;
    for (int i = tid; i < 4096; i += 256) {
        int r = i >> 6, cc = i & 63;
        t[r][cc] = (sizeof(T) == 2) ? ((const us*)W)[(size_t)(bi + r) * DIM_ + bj + cc]
                                    : f2b(ldT(W + (size_t)(bi + r) * DIM_ + bj + cc));
    }
    __syncthreads();
    for (int i = tid; i < 4096; i += 256) {
        int r = i >> 6, cc = i & 63;
        WT[(size_t)(bj + r) * DIM_ + bi + cc] = t[cc][r];
    }
}
__global__ void wt_kernel(const int* flag, const void* W, us* WT) {
    if (*flag) wt_body<us>((const us*)W, WT);
    else wt_body<float>((const float*)W, WT);
}

// ---------------- unified LDS-staged MFMA MLP ----------------
// fp32 weights: convert during staging (dwordx4 loads -> pack bf16 -> ds_write_b128).
// bf16 weights: async global_load_lds. Same swizzled layout + MFMA loop for both.
// XCD-aware 1D grid: blocks sharing a W m-tile differ by MT*KALL (== 0 mod 8) -> same XCD.
template <int M, int KTOT, int L1>
__global__ __launch_bounds__(256) void mlp_one(const int* flag, const void* Wv,
        const void* biasv, const void* ppv, const void* pgv, const us* X, us* Y) {
    constexpr int MT = M / 64;
    int flagv = *flag;
    __shared__ us SM[16384];
    us* As = SM;
    us* Bs = SM + 8192;
    int bx = blockIdx.x;
    int nt = bx / (MT * KALL);
    int rem = bx - nt * (MT * KALL);
    int e = rem % KALL;
    int mt = rem / KALL;
    int tid = threadIdx.x, w = tid >> 6, lane = tid & 63;
    int lm = lane & 15, quad = lane >> 4;
    const int RS = L1 ? 1024 : KTOT;
    int s0 = nt * 64;
    int srow = tid >> 4;
    int csrc = (tid & 15) ^ (srow & 7);
    us* lA = As + tid * 8;
    us* lB = Bs + tid * 8;
    const size_t arow = (size_t)e * M + mt * 64 + srow;
    const us*    AbB = (const us*)Wv + arow * KTOT + csrc * 8;
    const float* AbF = (const float*)Wv + arow * KTOT + csrc * 8;
    const us* Xbase = X + ((size_t)(L1 ? 0 : e * NSETS) + s0 + srow) * RS + csrc * 8;
    const us* PbB = nullptr;
    const float* PbF = nullptr;
    if (L1) {
        PbB = (const us*)(nt < 2 ? ppv : pgv) + (size_t)e * DIM_ + csrc * 8;
        PbF = (const float*)(nt < 2 ? ppv : pgv) + (size_t)e * DIM_ + csrc * 8;
    }
    f32x4 acc[4];
#pragma unroll
    for (int j = 0; j < 4; ++j) acc[j] = (f32x4){0.f, 0.f, 0.f, 0.f};
    int ar = w * 16 + lm, aswz = ar & 7;

    for (int k0 = 0; k0 < KTOT; k0 += 128) {
        __syncthreads();
        if (flagv) {
#pragma unroll
            for (int i = 0; i < 4; ++i)
                gload_lds16(AbB + (size_t)(i * 16) * KTOT + k0, lA + i * 2048);
        } else {
#pragma unroll
            for (int i = 0; i < 4; ++i)
                *(bf16x8*)(lA + i * 2048) = loadA(AbF + (size_t)(i * 16) * KTOT + k0);
        }
        if (!L1 || k0 < 1024) {
#pragma unroll
            for (int i = 0; i < 4; ++i)
                gload_lds16(Xbase + (size_t)(i * 16) * RS + k0, lB + i * 2048);
        } else if (flagv) {
#pragma unroll
            for (int i = 0; i < 4; ++i)
                gload_lds16(PbB + (k0 - 1024), lB + i * 2048);
        } else {
            bf16x8 v = loadA(PbF + (k0 - 1024));
#pragma unroll
            for (int i = 0; i < 4; ++i)
                *(bf16x8*)(lB + i * 2048) = v;
        }
        __syncthreads();
#pragma unroll
        for (int ks = 0; ks < 4; ++ks) {
            int cg = ks * 4 + quad;
            bf16x8 a = *(const bf16x8*)(As + ar * 128 + ((cg ^ aswz) * 8));
#pragma unroll
            for (int j = 0; j < 4; ++j) {
                int br = j * 16 + lm;
                bf16x8 b = *(const bf16x8*)(Bs + br * 128 + ((cg ^ (br & 7)) * 8));
                acc[j] = __builtin_amdgcn_mfma_f32_16x16x32_bf16(a, b, acc[j], 0, 0, 0);
            }
        }
    }
    int m0 = mt * 64 + w * 16 + quad * 4;
    float bv[4];
#pragma unroll
    for (int r = 0; r < 4; ++r)
        bv[r] = flagv ? b2f(((const us*)biasv)[(size_t)e * M + m0 + r])
                      : ((const float*)biasv)[(size_t)e * M + m0 + r];
#pragma unroll
    for (int j = 0; j < 4; ++j) {
        int s = s0 + j * 16 + lm;
        us4 pk;
#pragma unroll
        for (int r = 0; r < 4; ++r) {
            float v = acc[j][r] + bv[r];
            v = v > 0.f ? v : 0.01f * v;
            pk[r] = f2b(v);
        }
        *(us4*)(Y + ((size_t)e * NSETS + s) * M + m0) = pk;
    }
}

// ---------------- fold: CTXW = CTX @ W (probe rows) ----------------
__global__ void fold_kernel(const us* CTX, const us* WT, us* CTXW) {
    int nt = blockIdx.x, mtb = blockIdx.y;
    int e = mtb >> 1, sub = mtb & 1;
    int row0 = e * NSETS + sub * 64;
    int tid = threadIdx.x, w = tid >> 6, lane = tid & 63;
    int lm = lane & 15, quad = lane >> 4, kq = quad * 8;
    const us* Ap = CTX + ((size_t)row0 + w * 16 + lm) * DIM_ + kq;
    int n0 = nt * 64;
    const us* Bp = WT + (size_t)(n0 + lm) * DIM_ + kq;
    f32x4 acc[4];
#pragma unroll
    for (int j = 0; j < 4; ++j) acc[j] = (f32x4){0.f, 0.f, 0.f, 0.f};
#pragma unroll 2
    for (int kc = 0; kc < DIM_; kc += 32) {
        bf16x8 a = *(const bf16x8*)(Ap + kc);
#pragma unroll
        for (int j = 0; j < 4; ++j) {
            bf16x8 b = *(const bf16x8*)(Bp + kc + (size_t)j * 16 * DIM_);
            acc[j] = __builtin_amdgcn_mfma_f32_16x16x32_bf16(a, b, acc[j], 0, 0, 0);
        }
    }
    int mrow = row0 + w * 16 + quad * 4;
#pragma unroll
    for (int j = 0; j < 4; ++j)
#pragma unroll
        for (int r = 0; r < 4; ++r)
            CTXW[(size_t)(mrow + r) * DIM_ + n0 + j * 16 + lm] = f2b(acc[j][r]);
}

// ---------------- s0 = pb . ctx ----------------
template <typename T>
__device__ void s0a_body(const us* CTX, const T* pb, float* S0A) {
    int tid = threadIdx.x, w = tid >> 6, lane = tid & 63;
    int row = blockIdx.x * 4 + w;
    bf16x8 cv = *(const bf16x8*)(CTX + (size_t)row * DIM_ + lane * 8);
    float s = 0.f;
#pragma unroll
    for (int j = 0; j < 8; ++j) s += b2f((us)cv[j]) * ldT(pb + lane * 8 + j);
#pragma unroll
    for (int off = 32; off >= 1; off >>= 1) s += __shfl_xor(s, off, 64);
    if (lane == 0) S0A[row] = s;
}
__global__ void s0a_kernel(const int* flag, const us* CTX, const void* pb, float* S0A) {
    if (*flag) s0a_body<us>(CTX, (const us*)pb, S0A);
    else s0a_body<float>(CTX, (const float*)pb, S0A);
}

// ---------------- score: feat @ ctx^T via MFMA ----------------
template <typename T>
__device__ void score_body(const T* probes, const T* gallery, const int* plen,
                           const int* glen, float* wsf) {
    int bx = blockIdx.x, set, base, L;
    decode64(bx, set, base, L);
    bool probe = set < NPROBE;
    int len = probe ? plen[set] : glen[set - NPROBE];
    int len_eff = min(max(len, 1), L);
    if (base >= len_eff) return;
    const T* feat = probe ? probes + (size_t)set * L * DIM_
                          : gallery + (size_t)(set - NPROBE) * L * DIM_;
    int tid = threadIdx.x, w = tid >> 6, lane = tid & 63;
    int lm = lane & 15, quad = lane >> 4;
    const int* idx4 = (const int*)(wsf + F_IDX);
    const us* CTXW = (const us*)(wsf + F_CTXW);
    const us* CTXR = (const us*)(wsf + F_CTX);
    bf16x8 bq[16];
    float s0v = 0.f;
    if (lm < 4) {
        int row = idx4[set * 4 + lm] * NSETS + set;
        const us* src = (probe ? CTXW : CTXR) + (size_t)row * DIM_ + quad * 8;
#pragma unroll
        for (int s = 0; s < 16; ++s) bq[s] = *(const bf16x8*)(src + s * 32);
        s0v = probe ? wsf[F_S0A + row] : 0.f;
    } else {
#pragma unroll
        for (int s = 0; s < 16; ++s) bq[s] = (bf16x8){0, 0, 0, 0, 0, 0, 0, 0};
    }
    int m0 = base + w * 16;
    const T* Ap = feat + (size_t)(m0 + lm) * DIM_ + quad * 8;
    f32x4 acc = (f32x4){0.f, 0.f, 0.f, 0.f};
#pragma unroll
    for (int s = 0; s < 16; ++s) {
        bf16x8 a = loadA(Ap + s * 32);
        acc = __builtin_amdgcn_mfma_f32_16x16x32_bf16(a, bq[s], acc, 0, 0, 0);
    }
    if (lm < 4) {
        float* wq = wsf + F_WQ + (size_t)set * 2560;
#pragma unroll
        for (int r = 0; r < 4; ++r) {
            int row = m0 + quad * 4 + r;
            wq[(size_t)row * 5 + lm] = acc[r] + s0v;
        }
    }
}
__global__ __launch_bounds__(256, 3) void score_kernel(const int* flag, const void* probes,
        const void* gallery, const int* plen, const int* glen, float* wsf) {
    if (*flag) score_body<us>((const us*)probes, (const us*)gallery, plen, glen, wsf);
    else score_body<float>((const float*)probes, (const float*)gallery, plen, glen, wsf);
}

// ---------------- softmax over rows per (set,k), fold invn ----------------
__global__ void softmax_kernel(const int* plen, const int* glen, float* wsf) {
    int set = blockIdx.x, tid = threadIdx.x, k = tid >> 6, lane = tid & 63;
    bool probe = set < NPROBE;
    int L = probe ? LPR : LGA;
    int len = probe ? plen[set] : glen[set - NPROBE];
    int len_eff = min(max(len, 1), L);
    float* wq = wsf + F_WQ + (size_t)set * 2560;
    float cv[8];
    int n = 0;
    float m = -3e38f;
    for (int l = lane; l < len_eff; l += 64) {
        cv[n] = wq[(size_t)l * 5 + k];
        m = fmaxf(m, cv[n]);
        ++n;
    }
#pragma unroll
    for (int off = 32; off >= 1; off >>= 1) m = fmaxf(m, __shfl_xor(m, off, 64));
    float se = 0.f;
    for (int i = 0; i < n; ++i) se += __expf(cv[i] - m);
#pragma unroll
    for (int off = 32; off >= 1; off >>= 1) se += __shfl_xor(se, off, 64);
    float invs = 1.0f / se;
    n = 0;
    for (int l = lane; l < len_eff; l += 64) {
        wq[(size_t)l * 5 + k] = __expf(cv[n] - m) * invs * wq[(size_t)l * 5 + 4];
        ++n;
    }
}

// ---------------- accum ----------------
template <typename T>
__device__ void accum_body(const T* probes, const T* gallery, const int* plen,
                           const int* glen, float* wsf) {
    int bx = blockIdx.x, set = bx >> 2, c = bx & 3;
    bool probe = set < NPROBE;
    int L = probe ? LPR : LGA;
    const T* feat = probe ? probes + (size_t)set * L * DIM_
                          : gallery + (size_t)(set - NPROBE) * L * DIM_;
    int len = probe ? plen[set] : glen[set - NPROBE];
    int len_eff = min(max(len, 1), L);
    int r0 = c * (L / 4), r1 = min(r0 + L / 4, len_eff);
    int tid = threadIdx.x, g = tid >> 8, t = tid & 255;
    __shared__ float cf[512];
    __shared__ float pbuf[2048];
    int nr = r1 - r0;
    const float* wq = wsf + F_WQ + (size_t)set * 2560;
    for (int p = tid; p < nr * 4; p += 512)
        cf[p] = wq[(size_t)(r0 + (p >> 2)) * 5 + (p & 3)];
    __syncthreads();
    float ac[8] = {0.f, 0.f, 0.f, 0.f, 0.f, 0.f, 0.f, 0.f};
#pragma unroll 4
    for (int l = r0 + g; l < r1; l += 2) {
        float f0, f1;
        if constexpr (sizeof(T) == 2) {
            unsigned u = *(const unsigned*)((const us*)feat + (size_t)l * DIM_ + t * 2);
            f0 = __uint_as_float(u << 16);
            f1 = __uint_as_float(u & 0xFFFF0000u);
        } else {
            const T* rp = feat + (size_t)l * DIM_ + t * 2;
            f0 = rp[0]; f1 = rp[1];
        }
        f32x4 cc = *(const f32x4*)&cf[(l - r0) * 4];
#pragma unroll
        for (int k = 0; k < 4; ++k) {
            ac[k * 2] += f0 * cc[k];
            ac[k * 2 + 1] += f1 * cc[k];
        }
    }
    if (g == 1) {
#pragma unroll
        for (int i = 0; i < 8; ++i) pbuf[i * 256 + t] = ac[i];
    }
    __syncthreads();
    if (g == 0) {
        float* P = wsf + F_ACC + (size_t)bx * 2048;
#pragma unroll
        for (int k = 0; k < 4; ++k) {
            P[k * 512 + t * 2] = ac[k * 2] + pbuf[(k * 2) * 256 + t];
            P[k * 512 + t * 2 + 1] = ac[k * 2 + 1] + pbuf[(k * 2 + 1) * 256 + t];
        }
    }
}
__global__ __launch_bounds__(512) void accum_kernel(const int* flag, const void* probes,
        const void* gallery, const int* plen, const int* glen, float* wsf) {
    if (*flag) accum_body<us>((const us*)probes, (const us*)gallery, plen, glen, wsf);
    else accum_body<float>((const float*)probes, (const float*)gallery, plen, glen, wsf);
}

// ---------------- reduce ----------------
template <typename T>
__device__ void reduce_body(const float* wsf, T* dout) {
    int set = blockIdx.x, d = threadIdx.x;
    const float* A = wsf + F_ACC + (size_t)set * 4 * 2048;
    size_t ob = (set < NPROBE) ? O_OUT1 + (size_t)set * 2048
                               : O_OUT3 + (size_t)(set - NPROBE) * 2048;
#pragma unroll
    for (int k = 0; k < 4; ++k) {
        float s = A[k * 512 + d] + A[2048 + k * 512 + d] + A[4096 + k * 512 + d] + A[6144 + k * 512 + d];
        stT(dout + ob + k * 512 + d, s);
    }
}
__global__ __launch_bounds__(512) void reduce_kernel(const int* flag, const float* wsf, void* dout) {
    if (*flag) reduce_body<us>(wsf, (us*)dout);
    else reduce_body<float>(wsf, (float*)dout);
}

}  // namespace

extern "C" void kernel_launch(void* const* d_in, const int* in_sizes, int n_in,
                              void* d_out, int out_size, void* d_ws, size_t ws_size,
                              hipStream_t stream) {
    if (ws_size < WS_BYTES) return;
    float* wsf = (float*)d_ws;
    int* flag = (int*)d_ws;
    us* SUMM = (us*)(wsf + F_SUMM);
    us* H1 = (us*)(wsf + F_H1);
    us* H2 = (us*)(wsf + F_H2);
    us* CTXb = (us*)(wsf + F_CTX);
    us* CTXW = (us*)(wsf + F_CTXW);
    us* WT = (us*)(wsf + F_WT);
    const int* plen = (const int*)d_in[2];
    const int* glen = (const int*)d_in[3];

    detect_kernel<<<1, 64, 0, stream>>>((const unsigned int*)d_in[8], flag);
    proxies_kernel<<<22, 64, 0, stream>>>(flag, d_in[4], d_in[5], d_in[6], d_in[7], wsf, d_out);
    wt_kernel<<<dim3(8, 8), 256, 0, stream>>>(flag, d_in[8], WT);
    sums_kernel<<<NSETS * 4, 256, 0, stream>>>(flag, d_in[0], d_in[1], plen, glen, wsf);
    sims_kernel<<<1024, 256, 0, stream>>>(flag, d_in[0], d_in[1], plen, glen, d_in[6], wsf);
    statsfin_kernel<<<NSETS, 256, 0, stream>>>(plen, glen, wsf);

    mlp_one<1024, 1536, 1><<<3 * 16 * KALL, 256, 0, stream>>>(
        flag, d_in[10], d_in[11], d_in[4], d_in[5], SUMM, H1);
    mlp_one<1024, 1024, 0><<<3 * 16 * KALL, 256, 0, stream>>>(
        flag, d_in[12], d_in[13], d_in[4], d_in[5], H1, H2);
    mlp_one<512, 1024, 0><<<3 * 8 * KALL, 256, 0, stream>>>(
        flag, d_in[14], d_in[15], d_in[4], d_in[5], H2, CTXb);

    fold_kernel<<<dim3(8, 22), 256, 0, stream>>>(CTXb, WT, CTXW);
    s0a_kernel<<<528, 256, 0, stream>>>(flag, CTXb, d_in[9], wsf + F_S0A);
    score_kernel<<<1024, 256, 0, stream>>>(flag, d_in[0], d_in[1], plen, glen, wsf);
    softmax_kernel<<<NSETS, 256, 0, stream>>>(plen, glen, wsf);
    accum_kernel<<<NSETS * 4, 512, 0, stream>>>(flag, d_in[0], d_in[1], plen, glen, wsf);
    reduce_kernel<<<NSETS, 512, 0, stream>>>(flag, wsf, d_out);
}